// Round 3
// baseline (1466.679 us; speedup 1.0000x reference)
//
#include <hip/hip_runtime.h>
#include <hip/hip_bf16.h>

#define EPSBN 1e-5f
#define NKEYS 110592   // 48^3
#define SLICES 64

__device__ __forceinline__ unsigned fmap(float f){
  unsigned u = __float_as_uint(f);
  return (u & 0x80000000u) ? ~u : (u | 0x80000000u);
}
__device__ __forceinline__ float funmap(unsigned k){
  unsigned u = (k & 0x80000000u) ? (k & 0x7fffffffu) : ~k;
  return __uint_as_float(u);
}
__device__ __forceinline__ float bf2f(ushort u){ return __uint_as_float(((unsigned)u)<<16); }
__device__ __forceinline__ ushort f2bf(float f){
  unsigned u = __float_as_uint(f);
  unsigned r = u + 0x7fffu + ((u>>16)&1u);
  return (ushort)(r>>16);
}

// ---------------- zero scratch ----------------
__global__ __launch_bounds__(256) void k_zero(uint4* __restrict__ p, size_t n16){
  size_t i = (size_t)blockIdx.x*256 + threadIdx.x;
  size_t stride = (size_t)gridDim.x*256;
  uint4 z = make_uint4(0,0,0,0);
  for (; i < n16; i += stride) p[i] = z;
}

// ---------------- voxel unique ----------------
__global__ __launch_bounds__(256) void k_keys(const int* __restrict__ coords,
    unsigned* __restrict__ cnt, int n){
  int i = blockIdx.x*256 + threadIdx.x;
  if (i >= n) return;
  int x = coords[3*i+0], y = coords[3*i+1], z = coords[3*i+2];
  atomicAdd(&cnt[(unsigned)((x*48 + y)*48 + z)], 1u);
}

__global__ __launch_bounds__(256) void k_scan1(const unsigned* __restrict__ cnt,
    unsigned* __restrict__ rloc, unsigned* __restrict__ bsum){
  __shared__ unsigned ts[256];
  int t = threadIdx.x;
  int base = blockIdx.x*1024 + t*4;
  uint4 cv = *(const uint4*)&cnt[base];
  unsigned v0 = cv.x?1u:0u, v1 = cv.y?1u:0u, v2 = cv.z?1u:0u, v3 = cv.w?1u:0u;
  unsigned s = v0+v1+v2+v3;
  ts[t] = s;
  __syncthreads();
  for (int off=1; off<256; off<<=1){
    unsigned add = (t>=off) ? ts[t-off] : 0u;
    __syncthreads();
    ts[t] += add;
    __syncthreads();
  }
  unsigned run = ts[t] - s;
  rloc[base+0] = run; run += v0;
  rloc[base+1] = run; run += v1;
  rloc[base+2] = run; run += v2;
  rloc[base+3] = run;
  if (t == 255) bsum[blockIdx.x] = ts[255];
}

__global__ __launch_bounds__(128) void k_scan2(const unsigned* __restrict__ bsum,
    unsigned* __restrict__ boff){
  __shared__ unsigned ts[128];
  int t = threadIdx.x;
  unsigned v = (t < 108) ? bsum[t] : 0u;
  ts[t] = v;
  __syncthreads();
  for (int off=1; off<128; off<<=1){
    unsigned add = (t>=off) ? ts[t-off] : 0u;
    __syncthreads();
    ts[t] += add;
    __syncthreads();
  }
  boff[t] = ts[t] - v;   // boff[108] = total M
}

__global__ __launch_bounds__(256) void k_unq(const unsigned* __restrict__ cnt,
    const unsigned* __restrict__ rloc, const unsigned* __restrict__ boff,
    float* __restrict__ unq){
  int k = blockIdx.x*256 + threadIdx.x;
  if (k >= NKEYS) return;
  if (cnt[k] == 0) return;
  unsigned r = rloc[k] + boff[k>>10];
  float z = (float)(k % 48);
  float y = (float)((k/48) % 48);
  float x = (float)(k / 2304);
  unq[3*(size_t)r+0] = x; unq[3*(size_t)r+1] = y; unq[3*(size_t)r+2] = z;
}

__global__ __launch_bounds__(256) void k_pad(const unsigned* __restrict__ boff,
    float* __restrict__ unq, int n){
  int i = blockIdx.x*256 + threadIdx.x;
  if (i >= n) return;
  if ((unsigned)i >= boff[108]){
    unq[3*(size_t)i+0] = -1.f; unq[3*(size_t)i+1] = -1.f; unq[3*(size_t)i+2] = -1.f;
  }
}

__global__ __launch_bounds__(256) void k_inv(const int* __restrict__ coords,
    const unsigned* __restrict__ rloc, const unsigned* __restrict__ boff,
    unsigned* __restrict__ inv, int n){
  int i = blockIdx.x*256 + threadIdx.x;
  if (i >= n) return;
  int x = coords[3*i+0], y = coords[3*i+1], z = coords[3*i+2];
  unsigned k = (unsigned)((x*48 + y)*48 + z);
  inv[i] = rloc[k] + boff[k>>10];
}

// ---------------- BN stats on raw feats (9 cols) ----------------
__global__ __launch_bounds__(256) void k_stats0(const float* __restrict__ X,
    float* __restrict__ slices, int n){
  float s[9], ss[9];
  #pragma unroll
  for (int k=0;k<9;k++){ s[k]=0.f; ss[k]=0.f; }
  int stride = gridDim.x*256;
  for (int i = blockIdx.x*256 + threadIdx.x; i < n; i += stride){
    #pragma unroll
    for (int k=0;k<9;k++){
      float v = X[(size_t)i*9+k];
      s[k] += v; ss[k] += v*v;
    }
  }
  #pragma unroll
  for (int k=0;k<9;k++){
    #pragma unroll
    for (int off=32; off>0; off>>=1){
      s[k]  += __shfl_down(s[k],  off, 64);
      ss[k] += __shfl_down(ss[k], off, 64);
    }
  }
  if ((threadIdx.x & 63) == 0){
    float* sl = slices + (size_t)(blockIdx.x & (SLICES-1))*18;
    #pragma unroll
    for (int k=0;k<9;k++){
      atomicAdd(&sl[k],   s[k]);
      atomicAdd(&sl[9+k], ss[k]);
    }
  }
}

// reduce slices -> a = g*rsqrt(var+eps), c = b - mean*a   (ac = [a(M), c(M)])
__global__ void k_fin(const float* __restrict__ slices, int M, float invN,
    const float* __restrict__ g, const float* __restrict__ b, float* __restrict__ ac){
  int j = blockIdx.x*64 + threadIdx.x;
  if (j >= M) return;
  float s = 0.f, ss = 0.f;
  for (int sl = 0; sl < SLICES; sl++){
    s  += slices[(size_t)sl*2*M + j];
    ss += slices[(size_t)sl*2*M + M + j];
  }
  float mean = s*invN;
  float var = ss*invN - mean*mean;
  float a = g[j]*rsqrtf(var + EPSBN);
  ac[j] = a;
  ac[M+j] = b[j] - mean*a;
}

// ---------------- stats epilogue helper (DEPTH 1..3) ----------------
template<int M, int CPT>
__device__ __forceinline__ void do_stats(float (&acc)[8][CPT], float* ssum,
    float* slices, int rowbase, int ty, int tx, int t, int n, int bid){
  float s[CPT], ss[CPT];
  #pragma unroll
  for (int c=0;c<CPT;c++){ s[c]=0.f; ss[c]=0.f; }
  #pragma unroll
  for (int r=0;r<8;r++){
    int gr = rowbase + ty*8 + r;
    if (gr < n){
      #pragma unroll
      for (int c=0;c<CPT;c++){ float f=acc[r][c]; s[c]+=f; ss[c]+=f*f; }
    }
  }
  __syncthreads();                       // prior readers of aliased LDS done
  for (int e=t; e<2*M; e+=256) ssum[e] = 0.f;
  __syncthreads();
  #pragma unroll
  for (int c=0;c<CPT;c++){
    int j = tx + 32*c;
    atomicAdd(&ssum[j],   s[c]);
    atomicAdd(&ssum[M+j], ss[c]);
  }
  __syncthreads();
  float* gsl = slices + (size_t)(bid & (SLICES-1))*2*M;
  for (int e=t; e<2*M; e+=256) atomicAdd(&gsl[e], ssum[e]);
}

// ---------------- fused recompute chain ----------------
// DEPTH=1: t1 stats.  DEPTH=2: t2 stats.  DEPTH=3: t3 stats.  DEPTH=4: scatter-max of t4.
// Per block: 64 rows. 256 thr = 8 ty x 32 tx. Thread owns rows ty*8..+7, cols tx+32*c.
template<int DEPTH>
__global__ __launch_bounds__(256) void k_chain(
    const float* __restrict__ feats,
    const float* __restrict__ ac0, const float* __restrict__ w1, const float* __restrict__ b1,
    const float* __restrict__ ac1, const float* __restrict__ w2, const float* __restrict__ b2,
    const float* __restrict__ ac2, const float* __restrict__ w3, const float* __restrict__ b3,
    const float* __restrict__ ac3, const float* __restrict__ w4, const float* __restrict__ b4,
    const unsigned* __restrict__ inv, unsigned* __restrict__ pooled,
    float* __restrict__ slices, int n){
  __shared__ __align__(16) char smem[62240];
  float*  X0t = (float*)(smem);            // [9][72] f32
  float*  W1s = (float*)(smem + 2592);     // [9][64] f32
  ushort* T1  = (ushort*)(smem + 4896);    // [64][64] bf16
  ushort* T2  = (ushort*)(smem + 13088);   // [64][128] bf16
  float*  X3b = (float*)(smem + 13088);    // [64][33] f32 (stage3, aliases T2)
  float*  Wb  = (float*)(smem + 29472);    // [32][256] f32 max (weight stream)
  float*  Ws4 = (float*)(smem + 29472);    // [32][64] f32 (stage3, aliases Wb)
  float*  ssum= (float*)(smem);            // [2*M] f32 (stats, aliases X0t/W1s)

  int t = threadIdx.x, tx = t & 31, ty = t >> 5;
  int rowbase = blockIdx.x * 64;

  // ---- stage 0 load: bn0(feats) rows + w1 ----
  for (int e = t; e < 576; e += 256){
    int r = e / 9, k = e - r*9;
    int gr = rowbase + r;
    float v = (gr < n) ? feats[(size_t)gr*9 + k] : 0.f;
    X0t[k*72 + r] = fmaf(v, ac0[k], ac0[9+k]);
  }
  for (int e = t; e < 576; e += 256) W1s[e] = w1[e];
  __syncthreads();

  // ---- stage 0 compute: t1 = X0 @ w1 + b1 ----
  float a1v[8][2];
  {
    #pragma unroll
    for (int c=0;c<2;c++){
      float bj = b1[tx + 32*c];
      #pragma unroll
      for (int r=0;r<8;r++) a1v[r][c] = bj;
    }
    #pragma unroll
    for (int k=0;k<9;k++){
      float xr[8];
      #pragma unroll
      for (int r=0;r<8;r++) xr[r] = X0t[k*72 + ty*8 + r];
      float w0 = W1s[k*64 + tx], wA = W1s[k*64 + tx + 32];
      #pragma unroll
      for (int r=0;r<8;r++){
        a1v[r][0] = fmaf(xr[r], w0, a1v[r][0]);
        a1v[r][1] = fmaf(xr[r], wA, a1v[r][1]);
      }
    }
  }
  if constexpr (DEPTH == 1){
    do_stats<64,2>(a1v, ssum, slices, rowbase, ty, tx, t, n, blockIdx.x);
    return;
  }
  // ---- T1 = bf16(relu(bn1(t1))) ----
  #pragma unroll
  for (int c=0;c<2;c++){
    int j = tx + 32*c;
    float a = ac1[j], cc = ac1[64+j];
    #pragma unroll
    for (int r=0;r<8;r++)
      T1[(ty*8+r)*64 + j] = f2bf(fmaxf(fmaf(a1v[r][c], a, cc), 0.f));
  }
  __syncthreads();

  // ---- stage 1: t2 = T1 @ w2 + b2  (64x64 @ 64x128) ----
  float a2v[8][4];
  #pragma unroll
  for (int c=0;c<4;c++){
    float bj = b2[tx + 32*c];
    #pragma unroll
    for (int r=0;r<8;r++) a2v[r][c] = bj;
  }
  for (int kc=0; kc<64; kc+=32){
    __syncthreads();
    for (int e4=t; e4<1024; e4+=256){
      int kr = e4 >> 5, c4 = (e4 & 31) << 2;
      *(float4*)&Wb[kr*128 + c4] = *(const float4*)(w2 + (size_t)(kc+kr)*128 + c4);
    }
    __syncthreads();
    for (int kk4=0; kk4<32; kk4+=4){
      ushort4 xq[8];
      #pragma unroll
      for (int r=0;r<8;r++) xq[r] = *(const ushort4*)&T1[(ty*8+r)*64 + kc + kk4];
      #pragma unroll
      for (int u=0;u<4;u++){
        float wv[4];
        #pragma unroll
        for (int c=0;c<4;c++) wv[c] = Wb[(kk4+u)*128 + tx + 32*c];
        #pragma unroll
        for (int r=0;r<8;r++){
          float x = bf2f(((const ushort*)&xq[r])[u]);
          #pragma unroll
          for (int c=0;c<4;c++) a2v[r][c] = fmaf(x, wv[c], a2v[r][c]);
        }
      }
    }
  }
  if constexpr (DEPTH == 2){
    do_stats<128,4>(a2v, ssum, slices, rowbase, ty, tx, t, n, blockIdx.x);
    return;
  }
  // ---- T2 = bf16(relu(bn2(t2))) ----
  __syncthreads();   // T1 reads done before... (T2 distinct from T1; sync for Wb reuse below)
  #pragma unroll
  for (int c=0;c<4;c++){
    int j = tx + 32*c;
    float a = ac2[j], cc = ac2[128+j];
    #pragma unroll
    for (int r=0;r<8;r++)
      T2[(ty*8+r)*128 + j] = f2bf(fmaxf(fmaf(a2v[r][c], a, cc), 0.f));
  }
  __syncthreads();

  // ---- stage 2: t3 = T2 @ w3 + b3  (64x128 @ 128x256) ----
  float a3v[8][8];
  #pragma unroll
  for (int c=0;c<8;c++){
    float bj = b3[tx + 32*c];
    #pragma unroll
    for (int r=0;r<8;r++) a3v[r][c] = bj;
  }
  for (int kc=0; kc<128; kc+=32){
    __syncthreads();
    for (int e4=t; e4<2048; e4+=256){
      int kr = e4 >> 6, c4 = (e4 & 63) << 2;
      *(float4*)&Wb[kr*256 + c4] = *(const float4*)(w3 + (size_t)(kc+kr)*256 + c4);
    }
    __syncthreads();
    for (int kk4=0; kk4<32; kk4+=4){
      ushort4 xq[8];
      #pragma unroll
      for (int r=0;r<8;r++) xq[r] = *(const ushort4*)&T2[(ty*8+r)*128 + kc + kk4];
      #pragma unroll
      for (int u=0;u<4;u++){
        float wv[8];
        #pragma unroll
        for (int c=0;c<8;c++) wv[c] = Wb[(kk4+u)*256 + tx + 32*c];
        #pragma unroll
        for (int r=0;r<8;r++){
          float x = bf2f(((const ushort*)&xq[r])[u]);
          #pragma unroll
          for (int c=0;c<8;c++) a3v[r][c] = fmaf(x, wv[c], a3v[r][c]);
        }
      }
    }
  }
  if constexpr (DEPTH == 3){
    do_stats<256,8>(a3v, ssum, slices, rowbase, ty, tx, t, n, blockIdx.x);
    return;
  }

  // ---- DEPTH 4: bn3+relu in regs, then t4 = X3 @ w4 + b4, scatter-max ----
  float x3[8][8];
  #pragma unroll
  for (int c=0;c<8;c++){
    int j = tx + 32*c;
    float a = ac3[j], cc = ac3[256+j];
    #pragma unroll
    for (int r=0;r<8;r++) x3[r][c] = fmaxf(fmaf(a3v[r][c], a, cc), 0.f);
  }
  float acc4[8][2];
  #pragma unroll
  for (int c=0;c<2;c++){
    float bj = b4[tx + 32*c];
    #pragma unroll
    for (int r=0;r<8;r++) acc4[r][c] = bj;
  }
  for (int q=0; q<8; q++){
    __syncthreads();
    // thread's col group c==q holds cols tx+32*q  ->  X3b[row][tx]
    #pragma unroll
    for (int r=0;r<8;r++) X3b[(ty*8+r)*33 + tx] = x3[r][q];
    for (int e4=t; e4<512; e4+=256){
      int kr = e4 >> 4, c4 = (e4 & 15) << 2;
      *(float4*)&Ws4[kr*64 + c4] = *(const float4*)(w4 + (size_t)(q*32+kr)*64 + c4);
    }
    __syncthreads();
    for (int k2=0; k2<32; k2++){
      float xr[8];
      #pragma unroll
      for (int r=0;r<8;r++) xr[r] = X3b[(ty*8+r)*33 + k2];
      float w0 = Ws4[k2*64 + tx], wA = Ws4[k2*64 + tx + 32];
      #pragma unroll
      for (int r=0;r<8;r++){
        acc4[r][0] = fmaf(xr[r], w0, acc4[r][0]);
        acc4[r][1] = fmaf(xr[r], wA, acc4[r][1]);
      }
    }
  }
  #pragma unroll
  for (int r=0;r<8;r++){
    int gr = rowbase + ty*8 + r;
    if (gr < n){
      unsigned seg = inv[gr];
      atomicMax(&pooled[(size_t)seg*64 + tx],      fmap(acc4[r][0]));
      atomicMax(&pooled[(size_t)seg*64 + tx + 32], fmap(acc4[r][1]));
    }
  }
}

// ---------------- projection: out = relu(pooled @ wp + bp) ----------------
__global__ __launch_bounds__(256) void k_proj(const unsigned* __restrict__ pooled,
    const float* __restrict__ wp, const float* __restrict__ bp,
    const unsigned* __restrict__ boff, float* __restrict__ out, int n){
  __shared__ float wps[64][16];
  __shared__ float pl[16][66];
  int t = threadIdx.x;
  for (int e=t; e<1024; e+=256) wps[e>>4][e&15] = wp[e];
  unsigned M = boff[108];
  int rowbase = blockIdx.x*16;
  #pragma unroll
  for (int p=0;p<4;p++){
    int e = t + p*256;
    int r = e >> 6, k = e & 63;
    int gr = rowbase + r;
    float f = 0.f;
    if (gr < (int)M) f = funmap(pooled[(size_t)gr*64 + k]);
    pl[r][k] = f;
  }
  __syncthreads();
  int r = t >> 4, j = t & 15;
  int gr = rowbase + r;
  if (gr < n){
    float acc = bp[j];
    #pragma unroll
    for (int k=0;k<64;k++) acc = fmaf(pl[r][k], wps[k][j], acc);
    out[(size_t)gr*16 + j] = fmaxf(acc, 0.f);
  }
}

extern "C" void kernel_launch(void* const* d_in, const int* in_sizes, int n_in,
                              void* d_out, int out_size, void* d_ws, size_t ws_size,
                              hipStream_t stream){
  (void)n_in; (void)out_size;
  const float* feats  = (const float*)d_in[0];
  const int*   coords = (const int*)d_in[1];
  const float* g0=(const float*)d_in[2];  const float* bb0=(const float*)d_in[3];
  const float* g1=(const float*)d_in[4];  const float* bb1=(const float*)d_in[5];
  const float* g2=(const float*)d_in[6];  const float* bb2=(const float*)d_in[7];
  const float* g3=(const float*)d_in[8];  const float* bb3=(const float*)d_in[9];
  const float* w1=(const float*)d_in[10]; const float* b1=(const float*)d_in[11];
  const float* w2=(const float*)d_in[12]; const float* b2=(const float*)d_in[13];
  const float* w3=(const float*)d_in[14]; const float* b3=(const float*)d_in[15];
  const float* w4=(const float*)d_in[16]; const float* b4=(const float*)d_in[17];
  const float* wp=(const float*)d_in[18]; const float* bp=(const float*)d_in[19];
  int n = in_sizes[0]/9;

  char* ws = (char*)d_ws;
  size_t off = 0;
  auto alloc = [&](size_t bytes){ size_t o = off; off = (off + bytes + 255) & ~(size_t)255; return o; };
  size_t o_cnt  = alloc((size_t)NKEYS*4);            // zeroed
  size_t o_sl0  = alloc((size_t)SLICES*18*4);        // zeroed
  size_t o_sl1  = alloc((size_t)SLICES*128*4);       // zeroed
  size_t o_sl2  = alloc((size_t)SLICES*256*4);       // zeroed
  size_t o_sl3  = alloc((size_t)SLICES*512*4);       // zeroed
  size_t zero_end = off;
  size_t o_rloc = alloc((size_t)NKEYS*4);
  size_t o_bsum = alloc(128*4);
  size_t o_boff = alloc(128*4);
  size_t o_ac0  = alloc(18*4);
  size_t o_ac1  = alloc(128*4);
  size_t o_ac2  = alloc(256*4);
  size_t o_ac3  = alloc(512*4);
  size_t o_inv  = alloc((size_t)n*4);
  size_t npool = (n < NKEYS ? (size_t)n : (size_t)NKEYS);
  size_t pool_bytes = npool*64*4;
  size_t o_pool = alloc(pool_bytes);                 // zeroed
  if (ws_size < off) return;                         // can't run safely -> clean fail

  unsigned* cnt  = (unsigned*)(ws + o_cnt);
  unsigned* rloc = (unsigned*)(ws + o_rloc);
  unsigned* bsum = (unsigned*)(ws + o_bsum);
  unsigned* boff = (unsigned*)(ws + o_boff);
  unsigned* inv  = (unsigned*)(ws + o_inv);
  float* sl0 = (float*)(ws + o_sl0);
  float* sl1 = (float*)(ws + o_sl1);
  float* sl2 = (float*)(ws + o_sl2);
  float* sl3 = (float*)(ws + o_sl3);
  float* ac0 = (float*)(ws + o_ac0);
  float* ac1 = (float*)(ws + o_ac1);
  float* ac2 = (float*)(ws + o_ac2);
  float* ac3 = (float*)(ws + o_ac3);
  unsigned* pooled = (unsigned*)(ws + o_pool);

  float* out_pool = (float*)d_out;
  float* out_unq  = out_pool + (size_t)n*16;

  // zero: head (cnt + stat slices), then pooled
  {
    size_t n16 = zero_end/16;
    int zb = (int)((n16 + 255)/256); if (zb > 2048) zb = 2048;
    k_zero<<<zb,256,0,stream>>>((uint4*)ws, n16);
  }
  {
    size_t n16 = pool_bytes/16;
    int zb = (int)((n16 + 255)/256); if (zb > 2048) zb = 2048;
    k_zero<<<zb,256,0,stream>>>((uint4*)(ws + o_pool), n16);
  }

  int nb = (n + 255)/256;
  k_keys<<<nb,256,0,stream>>>(coords, cnt, n);
  k_scan1<<<NKEYS/1024,256,0,stream>>>(cnt, rloc, bsum);
  k_scan2<<<1,128,0,stream>>>(bsum, boff);
  k_unq<<<(NKEYS+255)/256,256,0,stream>>>(cnt, rloc, boff, out_unq);
  k_pad<<<nb,256,0,stream>>>(boff, out_unq, n);
  k_inv<<<nb,256,0,stream>>>(coords, rloc, boff, inv, n);

  k_stats0<<<512,256,0,stream>>>(feats, sl0, n);
  k_fin<<<1,64,0,stream>>>(sl0, 9, 1.f/(float)n, g0, bb0, ac0);

  int gb = (n+63)/64;
  k_chain<1><<<gb,256,0,stream>>>(feats, ac0,w1,b1, ac1,w2,b2, ac2,w3,b3, ac3,w4,b4, inv, pooled, sl1, n);
  k_fin<<<1,64,0,stream>>>(sl1, 64, 1.f/(float)n, g1, bb1, ac1);

  k_chain<2><<<gb,256,0,stream>>>(feats, ac0,w1,b1, ac1,w2,b2, ac2,w3,b3, ac3,w4,b4, inv, pooled, sl2, n);
  k_fin<<<2,64,0,stream>>>(sl2, 128, 1.f/(float)n, g2, bb2, ac2);

  k_chain<3><<<gb,256,0,stream>>>(feats, ac0,w1,b1, ac1,w2,b2, ac2,w3,b3, ac3,w4,b4, inv, pooled, sl3, n);
  k_fin<<<4,64,0,stream>>>(sl3, 256, 1.f/(float)n, g3, bb3, ac3);

  k_chain<4><<<gb,256,0,stream>>>(feats, ac0,w1,b1, ac1,w2,b2, ac2,w3,b3, ac3,w4,b4, inv, pooled, nullptr, n);

  k_proj<<<(n+15)/16,256,0,stream>>>(pooled, wp, bp, boff, out_pool, n);
}

// Round 4
// 514.071 us; speedup vs baseline: 2.8531x; 2.8531x over previous
//
#include <hip/hip_runtime.h>
#include <hip/hip_bf16.h>

#define EPSBN 1e-5f
#define NKEYS 110592   // 48^3
#define SLICES 64

typedef __attribute__((ext_vector_type(8))) short bf16x8;
typedef __attribute__((ext_vector_type(4))) float f32x4;

__device__ __forceinline__ unsigned fmap(float f){
  unsigned u = __float_as_uint(f);
  return (u & 0x80000000u) ? ~u : (u | 0x80000000u);
}
__device__ __forceinline__ float funmap(unsigned k){
  unsigned u = (k & 0x80000000u) ? (k & 0x7fffffffu) : ~k;
  return __uint_as_float(u);
}
__device__ __forceinline__ float bf2f(ushort u){ return __uint_as_float(((unsigned)u)<<16); }
__device__ __forceinline__ ushort f2bf(float f){
  unsigned u = __float_as_uint(f);
  unsigned r = u + 0x7fffu + ((u>>16)&1u);
  return (ushort)(r>>16);
}

// XOR-swizzled byte offset inside a row-major [R][KP] bf16 tile.
// KP=32 -> 64B rows, mask 3; KP>=64 -> mask 7. Keeps 16B alignment.
template<int KP>
__device__ __forceinline__ int swz(int row, int kbyte){
  constexpr int MASK = (KP >= 64) ? 7 : 3;
  return row*(KP*2) + (kbyte ^ ((row & MASK) << 4));
}

// ---------------- zero scratch ----------------
__global__ __launch_bounds__(256) void k_zero(uint4* __restrict__ p, size_t n16){
  size_t i = (size_t)blockIdx.x*256 + threadIdx.x;
  size_t stride = (size_t)gridDim.x*256;
  uint4 z = make_uint4(0,0,0,0);
  for (; i < n16; i += stride) p[i] = z;
}

// ---------------- weight prep: f32 [K][M] -> bf16 chunked [M][CK] swizzled ----------------
__global__ __launch_bounds__(256) void k_wprep(const float* __restrict__ w,
    ushort* __restrict__ wt, int K, int M, int CK, int mask){
  int nchunks = (K + CK - 1)/CK;
  int total = nchunks * M * CK;
  for (int idx = blockIdx.x*256 + threadIdx.x; idx < total; idx += gridDim.x*256){
    int c = idx / (M*CK);
    int rem = idx - c*M*CK;
    int row = rem / CK;          // output-feature index
    int kk = rem - row*CK;
    int k = c*CK + kk;
    float v = (k < K) ? w[(size_t)k*M + row] : 0.f;
    int inrow = (kk*2) ^ ((row & mask) << 4);
    size_t byte = ((size_t)c*M*CK + (size_t)row*CK)*2 + (size_t)inrow;
    *(ushort*)((char*)wt + byte) = f2bf(v);
  }
}

// ---------------- voxel unique ----------------
__global__ __launch_bounds__(256) void k_keys(const int* __restrict__ coords,
    unsigned* __restrict__ cnt, int n){
  int i = blockIdx.x*256 + threadIdx.x;
  if (i >= n) return;
  int x = coords[3*i+0], y = coords[3*i+1], z = coords[3*i+2];
  atomicAdd(&cnt[(unsigned)((x*48 + y)*48 + z)], 1u);
}

__global__ __launch_bounds__(256) void k_scan1(const unsigned* __restrict__ cnt,
    unsigned* __restrict__ rloc, unsigned* __restrict__ bsum){
  __shared__ unsigned ts[256];
  int t = threadIdx.x;
  int base = blockIdx.x*1024 + t*4;
  uint4 cv = *(const uint4*)&cnt[base];
  unsigned v0 = cv.x?1u:0u, v1 = cv.y?1u:0u, v2 = cv.z?1u:0u, v3 = cv.w?1u:0u;
  unsigned s = v0+v1+v2+v3;
  ts[t] = s;
  __syncthreads();
  for (int off=1; off<256; off<<=1){
    unsigned add = (t>=off) ? ts[t-off] : 0u;
    __syncthreads();
    ts[t] += add;
    __syncthreads();
  }
  unsigned run = ts[t] - s;
  rloc[base+0] = run; run += v0;
  rloc[base+1] = run; run += v1;
  rloc[base+2] = run; run += v2;
  rloc[base+3] = run;
  if (t == 255) bsum[blockIdx.x] = ts[255];
}

__global__ __launch_bounds__(128) void k_scan2(const unsigned* __restrict__ bsum,
    unsigned* __restrict__ boff){
  __shared__ unsigned ts[128];
  int t = threadIdx.x;
  unsigned v = (t < 108) ? bsum[t] : 0u;
  ts[t] = v;
  __syncthreads();
  for (int off=1; off<128; off<<=1){
    unsigned add = (t>=off) ? ts[t-off] : 0u;
    __syncthreads();
    ts[t] += add;
    __syncthreads();
  }
  boff[t] = ts[t] - v;   // boff[108] = total M
}

__global__ __launch_bounds__(256) void k_unq(const unsigned* __restrict__ cnt,
    const unsigned* __restrict__ rloc, const unsigned* __restrict__ boff,
    float* __restrict__ unq){
  int k = blockIdx.x*256 + threadIdx.x;
  if (k >= NKEYS) return;
  if (cnt[k] == 0) return;
  unsigned r = rloc[k] + boff[k>>10];
  float z = (float)(k % 48);
  float y = (float)((k/48) % 48);
  float x = (float)(k / 2304);
  unq[3*(size_t)r+0] = x; unq[3*(size_t)r+1] = y; unq[3*(size_t)r+2] = z;
}

__global__ __launch_bounds__(256) void k_pad(const unsigned* __restrict__ boff,
    float* __restrict__ unq, int n){
  int i = blockIdx.x*256 + threadIdx.x;
  if (i >= n) return;
  if ((unsigned)i >= boff[108]){
    unq[3*(size_t)i+0] = -1.f; unq[3*(size_t)i+1] = -1.f; unq[3*(size_t)i+2] = -1.f;
  }
}

__global__ __launch_bounds__(256) void k_inv(const int* __restrict__ coords,
    const unsigned* __restrict__ rloc, const unsigned* __restrict__ boff,
    unsigned* __restrict__ inv, int n){
  int i = blockIdx.x*256 + threadIdx.x;
  if (i >= n) return;
  int x = coords[3*i+0], y = coords[3*i+1], z = coords[3*i+2];
  unsigned k = (unsigned)((x*48 + y)*48 + z);
  inv[i] = rloc[k] + boff[k>>10];
}

// ---------------- BN stats on raw feats (9 cols) ----------------
__global__ __launch_bounds__(256) void k_stats0(const float* __restrict__ X,
    float* __restrict__ slices, int n){
  float s[9], ss[9];
  #pragma unroll
  for (int k=0;k<9;k++){ s[k]=0.f; ss[k]=0.f; }
  int stride = gridDim.x*256;
  for (int i = blockIdx.x*256 + threadIdx.x; i < n; i += stride){
    #pragma unroll
    for (int k=0;k<9;k++){
      float v = X[(size_t)i*9+k];
      s[k] += v; ss[k] += v*v;
    }
  }
  #pragma unroll
  for (int k=0;k<9;k++){
    #pragma unroll
    for (int off=32; off>0; off>>=1){
      s[k]  += __shfl_down(s[k],  off, 64);
      ss[k] += __shfl_down(ss[k], off, 64);
    }
  }
  if ((threadIdx.x & 63) == 0){
    float* sl = slices + (size_t)(blockIdx.x & (SLICES-1))*18;
    #pragma unroll
    for (int k=0;k<9;k++){
      atomicAdd(&sl[k],   s[k]);
      atomicAdd(&sl[9+k], ss[k]);
    }
  }
}

// reduce slices -> a = g*rsqrt(var+eps), c = b - mean*a   (ac = [a(M), c(M)])
// NOTE: stats are over the RAW (bias-free) pre-BN activations; the linear bias
// cancels inside training-mode BN, so c = b - mean_raw*a is exact.
__global__ void k_fin(const float* __restrict__ slices, int M, float invN,
    const float* __restrict__ g, const float* __restrict__ b, float* __restrict__ ac){
  int j = blockIdx.x*64 + threadIdx.x;
  if (j >= M) return;
  float s = 0.f, ss = 0.f;
  for (int sl = 0; sl < SLICES; sl++){
    s  += slices[(size_t)sl*2*M + j];
    ss += slices[(size_t)sl*2*M + M + j];
  }
  float mean = s*invN;
  float var = ss*invN - mean*mean;
  float a = g[j]*rsqrtf(var + EPSBN);
  ac[j] = a;
  ac[M+j] = b[j] - mean*a;
}

// ---------------- fused MFMA recompute chain ----------------
// 64 rows/block, 256 thr = 4 waves. 16x16x32 bf16 MFMA.
// A-frag: lane(16g+i) holds X[i][8g..8g+7]; B-frag: lane(16g+j) holds W[8g..][j]
// (from Wt[j][8g..] row-major); D: lane(16g+j) reg r -> Y[4g+r][j].
// DEPTH=1/2/3: accumulate raw stats for bn1/2/3.  DEPTH=4: scatter-max of t4.
template<int DEPTH>
__global__ __launch_bounds__(256) void k_chain(
    const float* __restrict__ feats, const float* __restrict__ ac0,
    const ushort* __restrict__ w1t, const float* __restrict__ ac1,
    const ushort* __restrict__ w2t, const float* __restrict__ ac2,
    const ushort* __restrict__ w3t, const float* __restrict__ ac3,
    const ushort* __restrict__ w4t, const float* __restrict__ b4,
    const unsigned* __restrict__ inv, unsigned* __restrict__ pooled,
    float* __restrict__ slices, int n){
  __shared__ __align__(16) char smem[45056];
  char* X0 = smem;                  // [64][32]  bf16 swz<32>
  char* T1 = smem + 4096;           // [64][64]  bf16 swz<64>
  char* T2 = smem + 12288;          // [64][128] bf16 swz<128>
  char* WB = smem + 28672;          // 16KB weight stream buffer
  char* X3 = smem;                  // [64][256] bf16 swz<256> (stage3, aliases X0..WB[0:4K))
  char* W4B = smem + 32768;         // 8KB w4 k-chunk (stage3)

  int t = threadIdx.x;
  int lane = t & 63, w = t >> 6;
  int lrow = lane & 15, lgrp = lane >> 4;
  int rowbase = blockIdx.x * 64;

  // ---- stage 0: X0 = bn0(feats) (zero-padded to K=32, zero rows >= n) ----
  for (int e = t; e < 2048; e += 256){
    int row = e >> 5, k = e & 31;
    int gr = rowbase + row;
    float v = (k < 9 && gr < n) ? fmaf(feats[(size_t)gr*9 + k], ac0[k], ac0[9+k]) : 0.f;
    *(ushort*)(X0 + swz<32>(row, k*2)) = f2bf(v);
  }
  ((uint4*)WB)[t] = ((const uint4*)w1t)[t];   // 4KB
  __syncthreads();

  f32x4 acc0[4] = {};
  {
    int kb = lgrp*16;
    bf16x8 b = *(const bf16x8*)(WB + swz<32>(w*16 + lrow, kb));
    #pragma unroll
    for (int rb = 0; rb < 4; rb++){
      bf16x8 a = *(const bf16x8*)(X0 + swz<32>(rb*16 + lrow, kb));
      acc0[rb] = __builtin_amdgcn_mfma_f32_16x16x32_bf16(a, b, acc0[rb], 0,0,0);
    }
  }

  if constexpr (DEPTH == 1){
    float s = 0.f, ss = 0.f;
    #pragma unroll
    for (int rb=0;rb<4;rb++)
      #pragma unroll
      for (int r=0;r<4;r++){ float f = acc0[rb][r]; s += f; ss += f*f; }
    __syncthreads();
    float* ssum = (float*)smem;
    if (t < 128) ssum[t] = 0.f;
    __syncthreads();
    int j = w*16 + lrow;
    atomicAdd(&ssum[j], s); atomicAdd(&ssum[64+j], ss);
    __syncthreads();
    float* gsl = slices + (size_t)(blockIdx.x & (SLICES-1))*128;
    if (t < 128) atomicAdd(&gsl[t], ssum[t]);
    return;
  }

  if constexpr (DEPTH >= 2){
  // ---- T1 = bf16(relu(bn1(acc0))), zero rows >= n ----
  {
    int j = w*16 + lrow;
    float a1 = ac1[j], c1 = ac1[64+j];
    #pragma unroll
    for (int rb=0;rb<4;rb++)
      #pragma unroll
      for (int r=0;r<4;r++){
        int row = rb*16 + 4*lgrp + r;
        float v = fmaxf(fmaf(acc0[rb][r], a1, c1), 0.f);
        if (rowbase + row >= n) v = 0.f;
        *(ushort*)(T1 + swz<64>(row, j*2)) = f2bf(v);
      }
  }
  #pragma unroll
  for (int p=0;p<4;p++) ((uint4*)WB)[t + 256*p] = ((const uint4*)w2t)[t + 256*p];  // 16KB
  __syncthreads();

  // ---- stage 1: 64x64 @ 64x128, wave w owns cols [w*32, w*32+32) ----
  f32x4 acc1[4][2] = {};
  #pragma unroll
  for (int ks=0; ks<2; ks++){
    int kb = ks*64 + lgrp*16;
    #pragma unroll
    for (int rb=0;rb<4;rb++){
      bf16x8 a = *(const bf16x8*)(T1 + swz<64>(rb*16 + lrow, kb));
      #pragma unroll
      for (int f=0;f<2;f++){
        bf16x8 b = *(const bf16x8*)(WB + swz<64>(w*32 + f*16 + lrow, kb));
        acc1[rb][f] = __builtin_amdgcn_mfma_f32_16x16x32_bf16(a, b, acc1[rb][f], 0,0,0);
      }
    }
  }

  if constexpr (DEPTH == 2){
    float s[2]={0.f,0.f}, ss[2]={0.f,0.f};
    #pragma unroll
    for (int rb=0;rb<4;rb++)
      #pragma unroll
      for (int f=0;f<2;f++)
        #pragma unroll
        for (int r=0;r<4;r++){ float v=acc1[rb][f][r]; s[f]+=v; ss[f]+=v*v; }
    __syncthreads();
    float* ssum = (float*)smem;
    if (t < 256) ssum[t] = 0.f;
    __syncthreads();
    #pragma unroll
    for (int f=0;f<2;f++){
      int j = w*32 + 16*f + lrow;
      atomicAdd(&ssum[j], s[f]); atomicAdd(&ssum[128+j], ss[f]);
    }
    __syncthreads();
    float* gsl = slices + (size_t)(blockIdx.x & (SLICES-1))*256;
    if (t < 256) atomicAdd(&gsl[t], ssum[t]);
    return;
  }

  if constexpr (DEPTH >= 3){
  // ---- T2 = bf16(relu(bn2(acc1))), zero rows >= n ----
  #pragma unroll
  for (int f=0;f<2;f++){
    int j = w*32 + 16*f + lrow;
    float a2 = ac2[j], c2 = ac2[128+j];
    #pragma unroll
    for (int rb=0;rb<4;rb++)
      #pragma unroll
      for (int r=0;r<4;r++){
        int row = rb*16 + 4*lgrp + r;
        float v = fmaxf(fmaf(acc1[rb][f][r], a2, c2), 0.f);
        if (rowbase + row >= n) v = 0.f;
        *(ushort*)(T2 + swz<128>(row, j*2)) = f2bf(v);
      }
  }
  __syncthreads();   // T2 ready; stage-1 WB reads done

  // ---- stage 2: 64x128 @ 128x256, phase c stages W3 rows [64c,64c+64);
  //      wave w owns row-block w (rows 16w..16w+15), all 64 cols of the chunk ----
  bf16x8 a2f[4];
  #pragma unroll
  for (int ks=0;ks<4;ks++)
    a2f[ks] = *(const bf16x8*)(T2 + swz<128>(w*16 + lrow, ks*64 + lgrp*16));

  f32x4 acc2[4][4] = {};
  #pragma unroll
  for (int c=0;c<4;c++){
    #pragma unroll
    for (int p=0;p<4;p++)
      ((uint4*)WB)[t + 256*p] = ((const uint4*)(w3t + c*8192))[t + 256*p];  // 16KB chunk
    __syncthreads();
    #pragma unroll
    for (int ks=0;ks<4;ks++){
      int kb = ks*64 + lgrp*16;
      #pragma unroll
      for (int f=0;f<4;f++){
        bf16x8 b = *(const bf16x8*)(WB + swz<128>(f*16 + lrow, kb));
        acc2[c][f] = __builtin_amdgcn_mfma_f32_16x16x32_bf16(a2f[ks], b, acc2[c][f], 0,0,0);
      }
    }
    __syncthreads();
  }

  if constexpr (DEPTH == 3){
    __syncthreads();
    float* ssum = (float*)smem;
    for (int e=t; e<512; e+=256) ssum[e] = 0.f;
    __syncthreads();
    #pragma unroll
    for (int c=0;c<4;c++)
      #pragma unroll
      for (int f=0;f<4;f++){
        int j = 64*c + 16*f + lrow;
        float s=0.f, ss=0.f;
        #pragma unroll
        for (int r=0;r<4;r++){ float v=acc2[c][f][r]; s+=v; ss+=v*v; }
        atomicAdd(&ssum[j], s); atomicAdd(&ssum[256+j], ss);
      }
    __syncthreads();
    float* gsl = slices + (size_t)(blockIdx.x & (SLICES-1))*512;
    for (int e=t; e<512; e+=256) atomicAdd(&gsl[e], ssum[e]);
    return;
  }

  if constexpr (DEPTH == 4){
  // ---- X3 = bf16(relu(bn3(acc2))), rows 16w..16w+15, zero rows >= n ----
  #pragma unroll
  for (int c=0;c<4;c++)
    #pragma unroll
    for (int f=0;f<4;f++){
      int j = 64*c + 16*f + lrow;
      float a3 = ac3[j], c3 = ac3[256+j];
      #pragma unroll
      for (int r=0;r<4;r++){
        int row = 16*w + 4*lgrp + r;
        float v = fmaxf(fmaf(acc2[c][f][r], a3, c3), 0.f);
        if (rowbase + row >= n) v = 0.f;
        *(ushort*)(X3 + swz<256>(row, j*2)) = f2bf(v);
      }
    }

  // ---- stage 3: 64x256 @ 256x64, wave w owns cols [w*16, w*16+16), k-chunked ----
  f32x4 acc3[4] = {};
  #pragma unroll
  for (int kc=0;kc<4;kc++){
    #pragma unroll
    for (int p=0;p<2;p++)
      ((uint4*)W4B)[t + 256*p] = ((const uint4*)(w4t + kc*4096))[t + 256*p];  // 8KB chunk
    __syncthreads();
    #pragma unroll
    for (int ks=0;ks<2;ks++){
      int kb = ks*64 + lgrp*16;
      bf16x8 b = *(const bf16x8*)(W4B + swz<64>(w*16 + lrow, kb));
      #pragma unroll
      for (int rb=0;rb<4;rb++){
        bf16x8 a = *(const bf16x8*)(X3 + swz<256>(rb*16 + lrow, kc*128 + kb));
        acc3[rb] = __builtin_amdgcn_mfma_f32_16x16x32_bf16(a, b, acc3[rb], 0,0,0);
      }
    }
    __syncthreads();
  }

  // ---- scatter-max ----
  {
    int j = w*16 + lrow;
    float bias4 = b4[j];
    #pragma unroll
    for (int rb=0;rb<4;rb++)
      #pragma unroll
      for (int r=0;r<4;r++){
        int gr = rowbase + 16*rb + 4*lgrp + r;
        if (gr < n){
          unsigned seg = inv[gr];
          atomicMax(&pooled[(size_t)seg*64 + j], fmap(acc3[rb][r] + bias4));
        }
      }
  }
  } // DEPTH==4
  } // DEPTH>=3
  } // DEPTH>=2
}

// ---------------- projection: out = relu(pooled @ wp + bp) ----------------
__global__ __launch_bounds__(256) void k_proj(const unsigned* __restrict__ pooled,
    const float* __restrict__ wp, const float* __restrict__ bp,
    const unsigned* __restrict__ boff, float* __restrict__ out, int n){
  __shared__ float wps[64][16];
  __shared__ float pl[16][66];
  int t = threadIdx.x;
  for (int e=t; e<1024; e+=256) wps[e>>4][e&15] = wp[e];
  unsigned M = boff[108];
  int rowbase = blockIdx.x*16;
  #pragma unroll
  for (int p=0;p<4;p++){
    int e = t + p*256;
    int r = e >> 6, k = e & 63;
    int gr = rowbase + r;
    float f = 0.f;
    if (gr < (int)M) f = funmap(pooled[(size_t)gr*64 + k]);
    pl[r][k] = f;
  }
  __syncthreads();
  int r = t >> 4, j = t & 15;
  int gr = rowbase + r;
  if (gr < n){
    float acc = bp[j];
    #pragma unroll
    for (int k=0;k<64;k++) acc = fmaf(pl[r][k], wps[k][j], acc);
    out[(size_t)gr*16 + j] = fmaxf(acc, 0.f);
  }
}

extern "C" void kernel_launch(void* const* d_in, const int* in_sizes, int n_in,
                              void* d_out, int out_size, void* d_ws, size_t ws_size,
                              hipStream_t stream){
  (void)n_in; (void)out_size;
  const float* feats  = (const float*)d_in[0];
  const int*   coords = (const int*)d_in[1];
  const float* g0=(const float*)d_in[2];  const float* bb0=(const float*)d_in[3];
  const float* g1=(const float*)d_in[4];  const float* bb1=(const float*)d_in[5];
  const float* g2=(const float*)d_in[6];  const float* bb2=(const float*)d_in[7];
  const float* g3=(const float*)d_in[8];  const float* bb3=(const float*)d_in[9];
  const float* w1=(const float*)d_in[10];
  const float* w2=(const float*)d_in[12];
  const float* w3=(const float*)d_in[14];
  const float* w4=(const float*)d_in[16]; const float* b4=(const float*)d_in[17];
  const float* wp=(const float*)d_in[18]; const float* bp=(const float*)d_in[19];
  int n = in_sizes[0]/9;

  char* ws = (char*)d_ws;
  size_t off = 0;
  auto alloc = [&](size_t bytes){ size_t o = off; off = (off + bytes + 255) & ~(size_t)255; return o; };
  size_t o_cnt  = alloc((size_t)NKEYS*4);            // zeroed
  size_t o_sl0  = alloc((size_t)SLICES*18*4);        // zeroed
  size_t o_sl1  = alloc((size_t)SLICES*128*4);       // zeroed
  size_t o_sl2  = alloc((size_t)SLICES*256*4);       // zeroed
  size_t o_sl3  = alloc((size_t)SLICES*512*4);       // zeroed
  size_t zero_end = off;
  size_t o_rloc = alloc((size_t)NKEYS*4);
  size_t o_bsum = alloc(128*4);
  size_t o_boff = alloc(128*4);
  size_t o_ac0  = alloc(18*4);
  size_t o_ac1  = alloc(128*4);
  size_t o_ac2  = alloc(256*4);
  size_t o_ac3  = alloc(512*4);
  size_t o_w1t  = alloc(2048*2);
  size_t o_w2t  = alloc(8192*2);
  size_t o_w3t  = alloc(32768*2);
  size_t o_w4t  = alloc(16384*2);
  size_t o_inv  = alloc((size_t)n*4);
  size_t npool = (n < NKEYS ? (size_t)n : (size_t)NKEYS);
  size_t pool_bytes = npool*64*4;
  size_t o_pool = alloc(pool_bytes);                 // zeroed
  if (ws_size < off) return;                         // clean fail if ws too small

  unsigned* cnt  = (unsigned*)(ws + o_cnt);
  unsigned* rloc = (unsigned*)(ws + o_rloc);
  unsigned* bsum = (unsigned*)(ws + o_bsum);
  unsigned* boff = (unsigned*)(ws + o_boff);
  unsigned* inv  = (unsigned*)(ws + o_inv);
  float* sl0 = (float*)(ws + o_sl0);
  float* sl1 = (float*)(ws + o_sl1);
  float* sl2 = (float*)(ws + o_sl2);
  float* sl3 = (float*)(ws + o_sl3);
  float* ac0 = (float*)(ws + o_ac0);
  float* ac1 = (float*)(ws + o_ac1);
  float* ac2 = (float*)(ws + o_ac2);
  float* ac3 = (float*)(ws + o_ac3);
  ushort* w1t = (ushort*)(ws + o_w1t);
  ushort* w2t = (ushort*)(ws + o_w2t);
  ushort* w3t = (ushort*)(ws + o_w3t);
  ushort* w4t = (ushort*)(ws + o_w4t);
  unsigned* pooled = (unsigned*)(ws + o_pool);

  float* out_pool = (float*)d_out;
  float* out_unq  = out_pool + (size_t)n*16;

  {
    size_t n16 = zero_end/16;
    int zb = (int)((n16 + 255)/256); if (zb > 2048) zb = 2048;
    k_zero<<<zb,256,0,stream>>>((uint4*)ws, n16);
  }
  {
    size_t n16 = pool_bytes/16;
    int zb = (int)((n16 + 255)/256); if (zb > 2048) zb = 2048;
    k_zero<<<zb,256,0,stream>>>((uint4*)(ws + o_pool), n16);
  }

  // weight prep (bf16, transposed, swizzled)
  k_wprep<<<8,256,0,stream>>>(w1, w1t, 9, 64, 32, 3);
  k_wprep<<<32,256,0,stream>>>(w2, w2t, 64, 128, 64, 7);
  k_wprep<<<128,256,0,stream>>>(w3, w3t, 128, 256, 128, 7);
  k_wprep<<<64,256,0,stream>>>(w4, w4t, 256, 64, 64, 7);

  int nb = (n + 255)/256;
  k_keys<<<nb,256,0,stream>>>(coords, cnt, n);
  k_scan1<<<NKEYS/1024,256,0,stream>>>(cnt, rloc, bsum);
  k_scan2<<<1,128,0,stream>>>(bsum, boff);
  k_unq<<<(NKEYS+255)/256,256,0,stream>>>(cnt, rloc, boff, out_unq);
  k_pad<<<nb,256,0,stream>>>(boff, out_unq, n);
  k_inv<<<nb,256,0,stream>>>(coords, rloc, boff, inv, n);

  k_stats0<<<512,256,0,stream>>>(feats, sl0, n);
  k_fin<<<1,64,0,stream>>>(sl0, 9, 1.f/(float)n, g0, bb0, ac0);

  int gb = (n+63)/64;
  k_chain<1><<<gb,256,0,stream>>>(feats, ac0, w1t, ac1, w2t, ac2, w3t, ac3, w4t, b4, inv, pooled, sl1, n);
  k_fin<<<1,64,0,stream>>>(sl1, 64, 1.f/(float)n, g1, bb1, ac1);

  k_chain<2><<<gb,256,0,stream>>>(feats, ac0, w1t, ac1, w2t, ac2, w3t, ac3, w4t, b4, inv, pooled, sl2, n);
  k_fin<<<2,64,0,stream>>>(sl2, 128, 1.f/(float)n, g2, bb2, ac2);

  k_chain<3><<<gb,256,0,stream>>>(feats, ac0, w1t, ac1, w2t, ac2, w3t, ac3, w4t, b4, inv, pooled, sl3, n);
  k_fin<<<4,64,0,stream>>>(sl3, 256, 1.f/(float)n, g3, bb3, ac3);

  k_chain<4><<<gb,256,0,stream>>>(feats, ac0, w1t, ac1, w2t, ac2, w3t, ac3, w4t, b4, inv, pooled, nullptr, n);

  k_proj<<<(n+15)/16,256,0,stream>>>(pooled, wp, bp, boff, out_pool, n);
}

// Round 5
// 374.415 us; speedup vs baseline: 3.9173x; 1.3730x over previous
//
#include <hip/hip_runtime.h>
#include <hip/hip_bf16.h>

#define EPSBN 1e-5f
#define NKEYS 110592   // 48^3
#define SLICES 64

typedef __attribute__((ext_vector_type(8))) short bf16x8;
typedef __attribute__((ext_vector_type(4))) float f32x4;

__device__ __forceinline__ unsigned fmap(float f){
  unsigned u = __float_as_uint(f);
  return (u & 0x80000000u) ? ~u : (u | 0x80000000u);
}
__device__ __forceinline__ float funmap(unsigned k){
  unsigned u = (k & 0x80000000u) ? (k & 0x7fffffffu) : ~k;
  return __uint_as_float(u);
}
__device__ __forceinline__ float bf2f(ushort u){ return __uint_as_float(((unsigned)u)<<16); }
__device__ __forceinline__ ushort f2bf(float f){
  unsigned u = __float_as_uint(f);
  unsigned r = u + 0x7fffu + ((u>>16)&1u);
  return (ushort)(r>>16);
}

// XOR-swizzled byte offset in row-major [R][KP] bf16 tile (T2 guideline-4 fix).
template<int KP>
__device__ __forceinline__ int swz(int row, int kbyte){
  constexpr int MASK = (KP >= 64) ? 7 : 3;
  return row*(KP*2) + (kbyte ^ ((row & MASK) << 4));
}

// ---------------- zero scratch ----------------
__global__ __launch_bounds__(256) void k_zero(uint4* __restrict__ p, size_t n16){
  size_t i = (size_t)blockIdx.x*256 + threadIdx.x;
  size_t stride = (size_t)gridDim.x*256;
  uint4 z = make_uint4(0,0,0,0);
  for (; i < n16; i += stride) p[i] = z;
}

// ---------------- weight prep: f32 [K][M] -> B-fragment order ----------------
// frag chunk c = ks*CT + ct; lane l = 16g + j; elem e:
//   wf[(c*64 + l)*8 + e] = bf16( W[32ks + 8g + e][16ct + j] ), 0 if k >= K
__global__ __launch_bounds__(256) void k_wprep(const float* __restrict__ w,
    ushort* __restrict__ wf, int K, int M){
  int CT = M >> 4;
  int KS = (K + 31) >> 5;
  int total = KS*CT*512;
  for (int idx = blockIdx.x*256 + threadIdx.x; idx < total; idx += gridDim.x*256){
    int e = idx & 7, l = (idx>>3) & 63, c = idx >> 9;
    int ct = c % CT, ks = c / CT;
    int g = l >> 4, j = l & 15;
    int k = ks*32 + g*8 + e, col = ct*16 + j;
    wf[idx] = (k < K) ? f2bf(w[(size_t)k*M + col]) : (ushort)0;
  }
}

// ---------------- voxel unique ----------------
__global__ __launch_bounds__(256) void k_keys(const int* __restrict__ coords,
    unsigned* __restrict__ cnt, int n){
  int i = blockIdx.x*256 + threadIdx.x;
  if (i >= n) return;
  int x = coords[3*i+0], y = coords[3*i+1], z = coords[3*i+2];
  atomicAdd(&cnt[(unsigned)((x*48 + y)*48 + z)], 1u);
}

__global__ __launch_bounds__(256) void k_scan1(const unsigned* __restrict__ cnt,
    unsigned* __restrict__ rloc, unsigned* __restrict__ bsum){
  __shared__ unsigned ts[256];
  int t = threadIdx.x;
  int base = blockIdx.x*1024 + t*4;
  uint4 cv = *(const uint4*)&cnt[base];
  unsigned v0 = cv.x?1u:0u, v1 = cv.y?1u:0u, v2 = cv.z?1u:0u, v3 = cv.w?1u:0u;
  unsigned s = v0+v1+v2+v3;
  ts[t] = s;
  __syncthreads();
  for (int off=1; off<256; off<<=1){
    unsigned add = (t>=off) ? ts[t-off] : 0u;
    __syncthreads();
    ts[t] += add;
    __syncthreads();
  }
  unsigned run = ts[t] - s;
  rloc[base+0] = run; run += v0;
  rloc[base+1] = run; run += v1;
  rloc[base+2] = run; run += v2;
  rloc[base+3] = run;
  if (t == 255) bsum[blockIdx.x] = ts[255];
}

__global__ __launch_bounds__(128) void k_scan2(const unsigned* __restrict__ bsum,
    unsigned* __restrict__ boff){
  __shared__ unsigned ts[128];
  int t = threadIdx.x;
  unsigned v = (t < 108) ? bsum[t] : 0u;
  ts[t] = v;
  __syncthreads();
  for (int off=1; off<128; off<<=1){
    unsigned add = (t>=off) ? ts[t-off] : 0u;
    __syncthreads();
    ts[t] += add;
    __syncthreads();
  }
  boff[t] = ts[t] - v;   // boff[108] = total M
}

__global__ __launch_bounds__(256) void k_unq(const unsigned* __restrict__ cnt,
    const unsigned* __restrict__ rloc, const unsigned* __restrict__ boff,
    float* __restrict__ unq){
  int k = blockIdx.x*256 + threadIdx.x;
  if (k >= NKEYS) return;
  if (cnt[k] == 0) return;
  unsigned r = rloc[k] + boff[k>>10];
  float z = (float)(k % 48);
  float y = (float)((k/48) % 48);
  float x = (float)(k / 2304);
  unq[3*(size_t)r+0] = x; unq[3*(size_t)r+1] = y; unq[3*(size_t)r+2] = z;
}

__global__ __launch_bounds__(256) void k_pad(const unsigned* __restrict__ boff,
    float* __restrict__ unq, int n){
  int i = blockIdx.x*256 + threadIdx.x;
  if (i >= n) return;
  if ((unsigned)i >= boff[108]){
    unq[3*(size_t)i+0] = -1.f; unq[3*(size_t)i+1] = -1.f; unq[3*(size_t)i+2] = -1.f;
  }
}

__global__ __launch_bounds__(256) void k_inv(const int* __restrict__ coords,
    const unsigned* __restrict__ rloc, const unsigned* __restrict__ boff,
    unsigned* __restrict__ inv, int n){
  int i = blockIdx.x*256 + threadIdx.x;
  if (i >= n) return;
  int x = coords[3*i+0], y = coords[3*i+1], z = coords[3*i+2];
  unsigned k = (unsigned)((x*48 + y)*48 + z);
  inv[i] = rloc[k] + boff[k>>10];
}

// ---------------- BN stats on raw feats (9 cols) ----------------
__global__ __launch_bounds__(256) void k_stats0(const float* __restrict__ X,
    float* __restrict__ slices, int n){
  float s[9], ss[9];
  #pragma unroll
  for (int k=0;k<9;k++){ s[k]=0.f; ss[k]=0.f; }
  int stride = gridDim.x*256;
  for (int i = blockIdx.x*256 + threadIdx.x; i < n; i += stride){
    #pragma unroll
    for (int k=0;k<9;k++){
      float v = X[(size_t)i*9+k];
      s[k] += v; ss[k] += v*v;
    }
  }
  #pragma unroll
  for (int k=0;k<9;k++){
    #pragma unroll
    for (int off=32; off>0; off>>=1){
      s[k]  += __shfl_down(s[k],  off, 64);
      ss[k] += __shfl_down(ss[k], off, 64);
    }
  }
  if ((threadIdx.x & 63) == 0){
    float* sl = slices + (size_t)(blockIdx.x & (SLICES-1))*18;
    #pragma unroll
    for (int k=0;k<9;k++){
      atomicAdd(&sl[k],   s[k]);
      atomicAdd(&sl[9+k], ss[k]);
    }
  }
}

// reduce slices -> a = g*rsqrt(var+eps), c = b - mean*a.  Stats are over RAW
// (bias-free) pre-BN activations; linear bias cancels in training-mode BN.
__global__ void k_fin(const float* __restrict__ slices, int M, float invN,
    const float* __restrict__ g, const float* __restrict__ b, float* __restrict__ ac){
  int j = blockIdx.x*64 + threadIdx.x;
  if (j >= M) return;
  float s = 0.f, ss = 0.f;
  for (int sl = 0; sl < SLICES; sl++){
    s  += slices[(size_t)sl*2*M + j];
    ss += slices[(size_t)sl*2*M + M + j];
  }
  float mean = s*invN;
  float var = ss*invN - mean*mean;
  float a = g[j]*rsqrtf(var + EPSBN);
  ac[j] = a;
  ac[M+j] = b[j] - mean*a;
}

// ---------------- fused MFMA recompute chain, barrier-free weight streaming ----------------
// 64 rows/block, 4 waves. B-frags loaded straight from frag-ordered global (L2-hot).
// A-frag: lane 16g+i = X[i][8g..8g+7]; D: lane 16g+j reg r -> row 4g+r, col j.
// DEPTH=1/2/3: raw stats for bn1/2/3. DEPTH=4: scatter-max of t4.
template<int DEPTH>
__global__ __launch_bounds__(256,2) void k_chain(
    const float* __restrict__ feats, const float* __restrict__ ac0,
    const ushort* __restrict__ w1f, const float* __restrict__ ac1,
    const ushort* __restrict__ w2f, const float* __restrict__ ac2,
    const ushort* __restrict__ w3f, const float* __restrict__ ac3,
    const ushort* __restrict__ w4f, const float* __restrict__ b4,
    const unsigned* __restrict__ inv, unsigned* __restrict__ pooled,
    float* __restrict__ slices, int n){
  constexpr int SMEM = (DEPTH==1) ? 4096 : (DEPTH==2) ? 12288 : (DEPTH==3) ? 28672 : 61440;
  __shared__ __align__(16) char smem[SMEM];
  char* X0 = smem;                  // [64][32]  bf16 swz<32>,  4KB

  int t = threadIdx.x;
  int lane = t & 63, w = t >> 6;
  int lrow = lane & 15, lgrp = lane >> 4;
  int rowbase = blockIdx.x * 64;

  // stage-1 B-frag (issued before staging; overlaps)
  bf16x8 b1 = *(const bf16x8*)(w1f + (size_t)(w*64 + lane)*8);

  // ---- X0 = bn0(feats), K padded to 32, rows >= n zeroed ----
  for (int e = t; e < 2048; e += 256){
    int row = e >> 5, k = e & 31;
    int gr = rowbase + row;
    float v = (k < 9 && gr < n) ? fmaf(feats[(size_t)gr*9 + k], ac0[k], ac0[9+k]) : 0.f;
    *(ushort*)(X0 + swz<32>(row, k*2)) = f2bf(v);
  }
  __syncthreads();

  // ---- stage 1: t1 = X0 @ w1 (wave w: cols 16w..16w+16) ----
  f32x4 acc0[4] = {};
  #pragma unroll
  for (int rb = 0; rb < 4; rb++){
    bf16x8 a = *(const bf16x8*)(X0 + swz<32>(rb*16 + lrow, lgrp*16));
    acc0[rb] = __builtin_amdgcn_mfma_f32_16x16x32_bf16(a, b1, acc0[rb], 0,0,0);
  }

  if constexpr (DEPTH == 1){
    float s = 0.f, ss = 0.f;
    #pragma unroll
    for (int rb=0;rb<4;rb++)
      #pragma unroll
      for (int r=0;r<4;r++){ float f = acc0[rb][r]; s += f; ss += f*f; }
    __syncthreads();
    float* ssum = (float*)smem;
    if (t < 128) ssum[t] = 0.f;
    __syncthreads();
    int j = w*16 + lrow;
    atomicAdd(&ssum[j], s); atomicAdd(&ssum[64+j], ss);
    __syncthreads();
    float* gsl = slices + (size_t)(blockIdx.x & (SLICES-1))*128;
    if (t < 128) atomicAdd(&gsl[t], ssum[t]);
    return;
  }

  if constexpr (DEPTH >= 2){
  char* T1 = smem + 4096;           // [64][64] bf16 swz<64>, 8KB
  // ---- T1 = bf16(relu(bn1(t1))), rows >= n zeroed ----
  {
    int j = w*16 + lrow;
    float a1 = ac1[j], c1 = ac1[64+j];
    #pragma unroll
    for (int rb=0;rb<4;rb++)
      #pragma unroll
      for (int r=0;r<4;r++){
        int row = rb*16 + 4*lgrp + r;
        float v = fmaxf(fmaf(acc0[rb][r], a1, c1), 0.f);
        if (rowbase + row >= n) v = 0.f;
        *(ushort*)(T1 + swz<64>(row, j*2)) = f2bf(v);
      }
  }
  __syncthreads();

  // ---- stage 2: 64x64 @ 64x128 (wave w: cols 32w..32w+32) ----
  f32x4 acc1[4][2] = {};
  #pragma unroll
  for (int ks=0; ks<2; ks++){
    bf16x8 bb[2];
    #pragma unroll
    for (int f=0;f<2;f++)
      bb[f] = *(const bf16x8*)(w2f + (size_t)((ks*8 + 2*w + f)*64 + lane)*8);
    #pragma unroll
    for (int rb=0;rb<4;rb++){
      bf16x8 a = *(const bf16x8*)(T1 + swz<64>(rb*16 + lrow, ks*64 + lgrp*16));
      #pragma unroll
      for (int f=0;f<2;f++)
        acc1[rb][f] = __builtin_amdgcn_mfma_f32_16x16x32_bf16(a, bb[f], acc1[rb][f], 0,0,0);
    }
  }

  if constexpr (DEPTH == 2){
    float s[2]={0.f,0.f}, ss[2]={0.f,0.f};
    #pragma unroll
    for (int rb=0;rb<4;rb++)
      #pragma unroll
      for (int f=0;f<2;f++)
        #pragma unroll
        for (int r=0;r<4;r++){ float v=acc1[rb][f][r]; s[f]+=v; ss[f]+=v*v; }
    __syncthreads();
    float* ssum = (float*)smem;
    ssum[t] = 0.f;
    __syncthreads();
    #pragma unroll
    for (int f=0;f<2;f++){
      int j = w*32 + 16*f + lrow;
      atomicAdd(&ssum[j], s[f]); atomicAdd(&ssum[128+j], ss[f]);
    }
    __syncthreads();
    float* gsl = slices + (size_t)(blockIdx.x & (SLICES-1))*256;
    atomicAdd(&gsl[t], ssum[t]);
    return;
  }

  if constexpr (DEPTH >= 3){
  char* T2 = smem + 12288;          // [64][128] bf16 swz<128>, 16KB
  // ---- T2 = bf16(relu(bn2(t2))), rows >= n zeroed ----
  #pragma unroll
  for (int f=0;f<2;f++){
    int j = w*32 + 16*f + lrow;
    float a2 = ac2[j], c2 = ac2[128+j];
    #pragma unroll
    for (int rb=0;rb<4;rb++)
      #pragma unroll
      for (int r=0;r<4;r++){
        int row = rb*16 + 4*lgrp + r;
        float v = fmaxf(fmaf(acc1[rb][f][r], a2, c2), 0.f);
        if (rowbase + row >= n) v = 0.f;
        *(ushort*)(T2 + swz<128>(row, j*2)) = f2bf(v);
      }
  }
  __syncthreads();

  // ---- stage 3: 64x128 @ 128x256 (wave w: cols 64w..64w+64, two 32-col halves) ----
  float s3[2][2], ss3[2][2];
  #pragma unroll
  for (int h=0; h<2; h++){
    f32x4 acc2[4][2] = {};
    #pragma unroll
    for (int ks=0; ks<4; ks++){
      bf16x8 bb[2];
      #pragma unroll
      for (int f=0;f<2;f++)
        bb[f] = *(const bf16x8*)(w3f + (size_t)((ks*16 + 4*w + 2*h + f)*64 + lane)*8);
      #pragma unroll
      for (int rb=0;rb<4;rb++){
        bf16x8 a = *(const bf16x8*)(T2 + swz<128>(rb*16 + lrow, ks*64 + lgrp*16));
        #pragma unroll
        for (int f=0;f<2;f++)
          acc2[rb][f] = __builtin_amdgcn_mfma_f32_16x16x32_bf16(a, bb[f], acc2[rb][f], 0,0,0);
      }
    }
    if constexpr (DEPTH == 3){
      #pragma unroll
      for (int f=0;f<2;f++){
        float s=0.f, ss=0.f;
        #pragma unroll
        for (int rb=0;rb<4;rb++)
          #pragma unroll
          for (int r=0;r<4;r++){ float v=acc2[rb][f][r]; s+=v; ss+=v*v; }
        s3[h][f]=s; ss3[h][f]=ss;
      }
    } else {
      // DEPTH 4: X3 = bf16(relu(bn3(t3))), rows >= n zeroed
      char* X3 = smem + 28672;      // [64][256] bf16 swz<256>, 32KB
      #pragma unroll
      for (int f=0;f<2;f++){
        int j = 64*w + 32*h + 16*f + lrow;
        float a3 = ac3[j], c3 = ac3[256+j];
        #pragma unroll
        for (int rb=0;rb<4;rb++)
          #pragma unroll
          for (int r=0;r<4;r++){
            int row = rb*16 + 4*lgrp + r;
            float v = fmaxf(fmaf(acc2[rb][f][r], a3, c3), 0.f);
            if (rowbase + row >= n) v = 0.f;
            *(ushort*)(X3 + swz<256>(row, j*2)) = f2bf(v);
          }
      }
    }
  }

  if constexpr (DEPTH == 3){
    __syncthreads();
    float* ssum = (float*)smem;
    for (int e=t; e<512; e+=256) ssum[e] = 0.f;
    __syncthreads();
    #pragma unroll
    for (int h=0;h<2;h++)
      #pragma unroll
      for (int f=0;f<2;f++){
        int j = 64*w + 32*h + 16*f + lrow;
        atomicAdd(&ssum[j], s3[h][f]); atomicAdd(&ssum[256+j], ss3[h][f]);
      }
    __syncthreads();
    float* gsl = slices + (size_t)(blockIdx.x & (SLICES-1))*512;
    for (int e=t; e<512; e+=256) atomicAdd(&gsl[e], ssum[e]);
    return;
  }

  if constexpr (DEPTH == 4){
  char* X3 = smem + 28672;
  __syncthreads();   // X3 complete across waves

  // ---- stage 4: 64x256 @ 256x64 (wave w: cols 16w..16w+16) ----
  f32x4 acc3[4] = {};
  #pragma unroll
  for (int ks=0; ks<8; ks++){
    bf16x8 b = *(const bf16x8*)(w4f + (size_t)((ks*4 + w)*64 + lane)*8);
    #pragma unroll
    for (int rb=0;rb<4;rb++){
      bf16x8 a = *(const bf16x8*)(X3 + swz<256>(rb*16 + lrow, ks*64 + lgrp*16));
      acc3[rb] = __builtin_amdgcn_mfma_f32_16x16x32_bf16(a, b, acc3[rb], 0,0,0);
    }
  }

  // ---- scatter-max ----
  {
    int j = w*16 + lrow;
    float bias4 = b4[j];
    #pragma unroll
    for (int rb=0;rb<4;rb++)
      #pragma unroll
      for (int r=0;r<4;r++){
        int gr = rowbase + 16*rb + 4*lgrp + r;
        if (gr < n){
          unsigned seg = inv[gr];
          atomicMax(&pooled[(size_t)seg*64 + j], fmap(acc3[rb][r] + bias4));
        }
      }
  }
  } // DEPTH==4
  } // DEPTH>=3
  } // DEPTH>=2
}

// ---------------- projection: out = relu(pooled @ wp + bp) ----------------
__global__ __launch_bounds__(256) void k_proj(const unsigned* __restrict__ pooled,
    const float* __restrict__ wp, const float* __restrict__ bp,
    const unsigned* __restrict__ boff, float* __restrict__ out, int n){
  __shared__ float wps[64][16];
  __shared__ float pl[16][66];
  int t = threadIdx.x;
  for (int e=t; e<1024; e+=256) wps[e>>4][e&15] = wp[e];
  unsigned M = boff[108];
  int rowbase = blockIdx.x*16;
  #pragma unroll
  for (int p=0;p<4;p++){
    int e = t + p*256;
    int r = e >> 6, k = e & 63;
    int gr = rowbase + r;
    float f = 0.f;
    if (gr < (int)M) f = funmap(pooled[(size_t)gr*64 + k]);
    pl[r][k] = f;
  }
  __syncthreads();
  int r = t >> 4, j = t & 15;
  int gr = rowbase + r;
  if (gr < n){
    float acc = bp[j];
    #pragma unroll
    for (int k=0;k<64;k++) acc = fmaf(pl[r][k], wps[k][j], acc);
    out[(size_t)gr*16 + j] = fmaxf(acc, 0.f);
  }
}

extern "C" void kernel_launch(void* const* d_in, const int* in_sizes, int n_in,
                              void* d_out, int out_size, void* d_ws, size_t ws_size,
                              hipStream_t stream){
  (void)n_in; (void)out_size;
  const float* feats  = (const float*)d_in[0];
  const int*   coords = (const int*)d_in[1];
  const float* g0=(const float*)d_in[2];  const float* bb0=(const float*)d_in[3];
  const float* g1=(const float*)d_in[4];  const float* bb1=(const float*)d_in[5];
  const float* g2=(const float*)d_in[6];  const float* bb2=(const float*)d_in[7];
  const float* g3=(const float*)d_in[8];  const float* bb3=(const float*)d_in[9];
  const float* w1=(const float*)d_in[10];
  const float* w2=(const float*)d_in[12];
  const float* w3=(const float*)d_in[14];
  const float* w4=(const float*)d_in[16]; const float* b4=(const float*)d_in[17];
  const float* wp=(const float*)d_in[18]; const float* bp=(const float*)d_in[19];
  int n = in_sizes[0]/9;

  char* ws = (char*)d_ws;
  size_t off = 0;
  auto alloc = [&](size_t bytes){ size_t o = off; off = (off + bytes + 255) & ~(size_t)255; return o; };
  size_t o_cnt  = alloc((size_t)NKEYS*4);            // zeroed
  size_t o_sl0  = alloc((size_t)SLICES*18*4);        // zeroed
  size_t o_sl1  = alloc((size_t)SLICES*128*4);       // zeroed
  size_t o_sl2  = alloc((size_t)SLICES*256*4);       // zeroed
  size_t o_sl3  = alloc((size_t)SLICES*512*4);       // zeroed
  size_t zero_end = off;
  size_t o_rloc = alloc((size_t)NKEYS*4);
  size_t o_bsum = alloc(128*4);
  size_t o_boff = alloc(128*4);
  size_t o_ac0  = alloc(18*4);
  size_t o_ac1  = alloc(128*4);
  size_t o_ac2  = alloc(256*4);
  size_t o_ac3  = alloc(512*4);
  size_t o_w1f  = alloc(2048*2);
  size_t o_w2f  = alloc(8192*2);
  size_t o_w3f  = alloc(32768*2);
  size_t o_w4f  = alloc(16384*2);
  size_t o_inv  = alloc((size_t)n*4);
  size_t npool = (n < NKEYS ? (size_t)n : (size_t)NKEYS);
  size_t pool_bytes = npool*64*4;
  size_t o_pool = alloc(pool_bytes);                 // zeroed
  if (ws_size < off) return;                         // clean fail if ws too small

  unsigned* cnt  = (unsigned*)(ws + o_cnt);
  unsigned* rloc = (unsigned*)(ws + o_rloc);
  unsigned* bsum = (unsigned*)(ws + o_bsum);
  unsigned* boff = (unsigned*)(ws + o_boff);
  unsigned* inv  = (unsigned*)(ws + o_inv);
  float* sl0 = (float*)(ws + o_sl0);
  float* sl1 = (float*)(ws + o_sl1);
  float* sl2 = (float*)(ws + o_sl2);
  float* sl3 = (float*)(ws + o_sl3);
  float* ac0 = (float*)(ws + o_ac0);
  float* ac1 = (float*)(ws + o_ac1);
  float* ac2 = (float*)(ws + o_ac2);
  float* ac3 = (float*)(ws + o_ac3);
  ushort* w1f = (ushort*)(ws + o_w1f);
  ushort* w2f = (ushort*)(ws + o_w2f);
  ushort* w3f = (ushort*)(ws + o_w3f);
  ushort* w4f = (ushort*)(ws + o_w4f);
  unsigned* pooled = (unsigned*)(ws + o_pool);

  float* out_pool = (float*)d_out;
  float* out_unq  = out_pool + (size_t)n*16;

  {
    size_t n16 = zero_end/16;
    int zb = (int)((n16 + 255)/256); if (zb > 2048) zb = 2048;
    k_zero<<<zb,256,0,stream>>>((uint4*)ws, n16);
  }
  {
    size_t n16 = pool_bytes/16;
    int zb = (int)((n16 + 255)/256); if (zb > 2048) zb = 2048;
    k_zero<<<zb,256,0,stream>>>((uint4*)(ws + o_pool), n16);
  }

  // weight prep (bf16, B-fragment order)
  k_wprep<<<8,256,0,stream>>>(w1, w1f, 9, 64);
  k_wprep<<<32,256,0,stream>>>(w2, w2f, 64, 128);
  k_wprep<<<128,256,0,stream>>>(w3, w3f, 128, 256);
  k_wprep<<<64,256,0,stream>>>(w4, w4f, 256, 64);

  int nb = (n + 255)/256;
  k_keys<<<nb,256,0,stream>>>(coords, cnt, n);
  k_scan1<<<NKEYS/1024,256,0,stream>>>(cnt, rloc, bsum);
  k_scan2<<<1,128,0,stream>>>(bsum, boff);
  k_unq<<<(NKEYS+255)/256,256,0,stream>>>(cnt, rloc, boff, out_unq);
  k_pad<<<nb,256,0,stream>>>(boff, out_unq, n);
  k_inv<<<nb,256,0,stream>>>(coords, rloc, boff, inv, n);

  k_stats0<<<512,256,0,stream>>>(feats, sl0, n);
  k_fin<<<1,64,0,stream>>>(sl0, 9, 1.f/(float)n, g0, bb0, ac0);

  int gb = (n+63)/64;
  k_chain<1><<<gb,256,0,stream>>>(feats, ac0, w1f, ac1, w2f, ac2, w3f, ac3, w4f, b4, inv, pooled, sl1, n);
  k_fin<<<1,64,0,stream>>>(sl1, 64, 1.f/(float)n, g1, bb1, ac1);

  k_chain<2><<<gb,256,0,stream>>>(feats, ac0, w1f, ac1, w2f, ac2, w3f, ac3, w4f, b4, inv, pooled, sl2, n);
  k_fin<<<2,64,0,stream>>>(sl2, 128, 1.f/(float)n, g2, bb2, ac2);

  k_chain<3><<<gb,256,0,stream>>>(feats, ac0, w1f, ac1, w2f, ac2, w3f, ac3, w4f, b4, inv, pooled, sl3, n);
  k_fin<<<4,64,0,stream>>>(sl3, 256, 1.f/(float)n, g3, bb3, ac3);

  k_chain<4><<<gb,256,0,stream>>>(feats, ac0, w1f, ac1, w2f, ac2, w3f, ac3, w4f, b4, inv, pooled, nullptr, n);

  k_proj<<<(n+15)/16,256,0,stream>>>(pooled, wp, bp, boff, out_pool, n);
}

// Round 6
// 334.714 us; speedup vs baseline: 4.3819x; 1.1186x over previous
//
#include <hip/hip_runtime.h>
#include <hip/hip_bf16.h>

#define EPSBN 1e-5f
#define NKEYS 110592   // 48^3
#define SLICES 64

typedef __attribute__((ext_vector_type(8))) short bf16x8;
typedef __attribute__((ext_vector_type(4))) float f32x4;

__device__ __forceinline__ unsigned fmap(float f){
  unsigned u = __float_as_uint(f);
  return (u & 0x80000000u) ? ~u : (u | 0x80000000u);
}
__device__ __forceinline__ float funmap(unsigned k){
  unsigned u = (k & 0x80000000u) ? (k & 0x7fffffffu) : ~k;
  return __uint_as_float(u);
}
__device__ __forceinline__ float bf2f(ushort u){ return __uint_as_float(((unsigned)u)<<16); }
__device__ __forceinline__ ushort f2bf(float f){
  unsigned u = __float_as_uint(f);
  unsigned r = u + 0x7fffu + ((u>>16)&1u);
  return (ushort)(r>>16);
}

// XOR-swizzled byte offset in row-major [R][KP] bf16 tile (bank-conflict fix).
template<int KP>
__device__ __forceinline__ int swz(int row, int kbyte){
  constexpr int MASK = (KP >= 64) ? 7 : 3;
  return row*(KP*2) + (kbyte ^ ((row & MASK) << 4));
}

__device__ __forceinline__ int tri(int k, int l){
  if (k > l){ int t=k; k=l; l=t; }
  return k*9 - (k*(k-1))/2 + (l-k);
}

// ---------------- zero scratch ----------------
__global__ __launch_bounds__(256) void k_zero(uint4* __restrict__ p, size_t n16){
  size_t i = (size_t)blockIdx.x*256 + threadIdx.x;
  size_t stride = (size_t)gridDim.x*256;
  uint4 z = make_uint4(0,0,0,0);
  for (; i < n16; i += stride) p[i] = z;
}

// ---------------- weight prep: f32 [K][M] -> B-fragment order ----------------
__global__ __launch_bounds__(256) void k_wprep(const float* __restrict__ w,
    ushort* __restrict__ wf, int K, int M){
  int CT = M >> 4;
  int KS = (K + 31) >> 5;
  int total = KS*CT*512;
  for (int idx = blockIdx.x*256 + threadIdx.x; idx < total; idx += gridDim.x*256){
    int e = idx & 7, l = (idx>>3) & 63, c = idx >> 9;
    int ct = c % CT, ks = c / CT;
    int g = l >> 4, j = l & 15;
    int k = ks*32 + g*8 + e, col = ct*16 + j;
    wf[idx] = (k < K) ? f2bf(w[(size_t)k*M + col]) : (ushort)0;
  }
}

// ---------------- voxel unique ----------------
__global__ __launch_bounds__(256) void k_keys(const int* __restrict__ coords,
    unsigned* __restrict__ cnt, int n){
  int i = blockIdx.x*256 + threadIdx.x;
  if (i >= n) return;
  int x = coords[3*i+0], y = coords[3*i+1], z = coords[3*i+2];
  atomicAdd(&cnt[(unsigned)((x*48 + y)*48 + z)], 1u);
}

__global__ __launch_bounds__(256) void k_scan1(const unsigned* __restrict__ cnt,
    unsigned* __restrict__ rloc, unsigned* __restrict__ bsum){
  __shared__ unsigned ts[256];
  int t = threadIdx.x;
  int base = blockIdx.x*1024 + t*4;
  uint4 cv = *(const uint4*)&cnt[base];
  unsigned v0 = cv.x?1u:0u, v1 = cv.y?1u:0u, v2 = cv.z?1u:0u, v3 = cv.w?1u:0u;
  unsigned s = v0+v1+v2+v3;
  ts[t] = s;
  __syncthreads();
  for (int off=1; off<256; off<<=1){
    unsigned add = (t>=off) ? ts[t-off] : 0u;
    __syncthreads();
    ts[t] += add;
    __syncthreads();
  }
  unsigned run = ts[t] - s;
  rloc[base+0] = run; run += v0;
  rloc[base+1] = run; run += v1;
  rloc[base+2] = run; run += v2;
  rloc[base+3] = run;
  if (t == 255) bsum[blockIdx.x] = ts[255];
}

__global__ __launch_bounds__(128) void k_scan2(const unsigned* __restrict__ bsum,
    unsigned* __restrict__ boff){
  __shared__ unsigned ts[128];
  int t = threadIdx.x;
  unsigned v = (t < 108) ? bsum[t] : 0u;
  ts[t] = v;
  __syncthreads();
  for (int off=1; off<128; off<<=1){
    unsigned add = (t>=off) ? ts[t-off] : 0u;
    __syncthreads();
    ts[t] += add;
    __syncthreads();
  }
  boff[t] = ts[t] - v;   // boff[108] = total M
}

__global__ __launch_bounds__(256) void k_unq(const unsigned* __restrict__ cnt,
    const unsigned* __restrict__ rloc, const unsigned* __restrict__ boff,
    float* __restrict__ unq){
  int k = blockIdx.x*256 + threadIdx.x;
  if (k >= NKEYS) return;
  if (cnt[k] == 0) return;
  unsigned r = rloc[k] + boff[k>>10];
  float z = (float)(k % 48);
  float y = (float)((k/48) % 48);
  float x = (float)(k / 2304);
  unq[3*(size_t)r+0] = x; unq[3*(size_t)r+1] = y; unq[3*(size_t)r+2] = z;
}

__global__ __launch_bounds__(256) void k_pad(const unsigned* __restrict__ boff,
    float* __restrict__ unq, int n){
  int i = blockIdx.x*256 + threadIdx.x;
  if (i >= n) return;
  if ((unsigned)i >= boff[108]){
    unq[3*(size_t)i+0] = -1.f; unq[3*(size_t)i+1] = -1.f; unq[3*(size_t)i+2] = -1.f;
  }
}

__global__ __launch_bounds__(256) void k_inv(const int* __restrict__ coords,
    const unsigned* __restrict__ rloc, const unsigned* __restrict__ boff,
    unsigned* __restrict__ inv, int n){
  int i = blockIdx.x*256 + threadIdx.x;
  if (i >= n) return;
  int x = coords[3*i+0], y = coords[3*i+1], z = coords[3*i+2];
  unsigned k = (unsigned)((x*48 + y)*48 + z);
  inv[i] = rloc[k] + boff[k>>10];
}

// ---------------- feats moments: s[9] = sum x, q[45] = sum x_k x_l (k<=l) ----------------
__global__ __launch_bounds__(256) void k_stats0x(const float* __restrict__ X,
    float* __restrict__ slices, int n){
  float s[9], q[45];
  #pragma unroll
  for (int k=0;k<9;k++) s[k]=0.f;
  #pragma unroll
  for (int i=0;i<45;i++) q[i]=0.f;
  int stride = gridDim.x*256;
  for (int i = blockIdx.x*256 + threadIdx.x; i < n; i += stride){
    float v[9];
    #pragma unroll
    for (int k=0;k<9;k++) v[k] = X[(size_t)i*9+k];
    int qi=0;
    #pragma unroll
    for (int k=0;k<9;k++){
      s[k] += v[k];
      #pragma unroll
      for (int l=k;l<9;l++) q[qi++] += v[k]*v[l];
    }
  }
  #pragma unroll
  for (int off=32; off>0; off>>=1){
    #pragma unroll
    for (int k=0;k<9;k++)  s[k] += __shfl_down(s[k], off, 64);
    #pragma unroll
    for (int i=0;i<45;i++) q[i] += __shfl_down(q[i], off, 64);
  }
  if ((threadIdx.x & 63) == 0){
    float* sl = slices + (size_t)(blockIdx.x & (SLICES-1))*54;
    #pragma unroll
    for (int k=0;k<9;k++)  atomicAdd(&sl[k],   s[k]);
    #pragma unroll
    for (int i=0;i<45;i++) atomicAdd(&sl[9+i], q[i]);
  }
}

// ---------------- ac0 + analytic ac1 from feats moments ----------------
// u_k = a0_k x_k + c0_k ; t1_j = sum_k u_k w1[k][j] (bias-free raw convention)
__global__ void k_fin01(const float* __restrict__ slices, float invN,
    const float* __restrict__ g0, const float* __restrict__ b0,
    const float* __restrict__ g1, const float* __restrict__ b1,
    const float* __restrict__ w1, float* __restrict__ ac0, float* __restrict__ ac1){
  __shared__ float red[54];
  int t = threadIdx.x;   // 64 threads
  if (t < 54){
    float a = 0.f;
    for (int sl=0; sl<SLICES; sl++) a += slices[(size_t)sl*54 + t];
    red[t] = a;
  }
  __syncthreads();
  float m[9], a0[9], c0[9], qb[45];
  #pragma unroll
  for (int k=0;k<9;k++) m[k] = red[k]*invN;
  #pragma unroll
  for (int i=0;i<45;i++) qb[i] = red[9+i]*invN;
  #pragma unroll
  for (int k=0;k<9;k++){
    float var = qb[tri(k,k)] - m[k]*m[k];
    a0[k] = g0[k]*rsqrtf(var + EPSBN);
    c0[k] = b0[k] - m[k]*a0[k];
  }
  if (t < 9){ ac0[t] = a0[t]; ac0[9+t] = c0[t]; }
  float wj[9];
  #pragma unroll
  for (int k=0;k<9;k++) wj[k] = w1[(size_t)k*64 + t];
  float mean = 0.f;
  #pragma unroll
  for (int k=0;k<9;k++) mean += (m[k]*a0[k] + c0[k])*wj[k];
  float e2 = 0.f;
  #pragma unroll
  for (int k=0;k<9;k++)
    #pragma unroll
    for (int l=0;l<9;l++){
      float U = a0[k]*a0[l]*qb[tri(k,l)] + a0[k]*c0[l]*m[k] + a0[l]*c0[k]*m[l] + c0[k]*c0[l];
      e2 += wj[k]*wj[l]*U;
    }
  float var = e2 - mean*mean;
  float a = g1[t]*rsqrtf(var + EPSBN);
  ac1[t] = a;
  ac1[64+t] = b1[t] - mean*a;
}

// reduce slices -> a = g*rsqrt(var+eps), c = b - mean*a.  Stats over RAW
// (bias-free) pre-BN activations; linear bias cancels in training-mode BN.
__global__ void k_fin(const float* __restrict__ slices, int M, float invN,
    const float* __restrict__ g, const float* __restrict__ b, float* __restrict__ ac){
  int j = blockIdx.x*64 + threadIdx.x;
  if (j >= M) return;
  float s = 0.f, ss = 0.f;
  for (int sl = 0; sl < SLICES; sl++){
    s  += slices[(size_t)sl*2*M + j];
    ss += slices[(size_t)sl*2*M + M + j];
  }
  float mean = s*invN;
  float var = ss*invN - mean*mean;
  float a = g[j]*rsqrtf(var + EPSBN);
  ac[j] = a;
  ac[M+j] = b[j] - mean*a;
}

// ---------------- fused MFMA recompute chain, barrier-free weight streaming ----------------
// 64 rows/block, 4 waves. B-frags loaded straight from frag-ordered global (L2-hot).
// DEPTH=2: t2 stats.  DEPTH=3: t3 stats.  DEPTH=4: scatter-max of t4.
template<int DEPTH>
__global__ __launch_bounds__(256,2) void k_chain(
    const float* __restrict__ feats, const float* __restrict__ ac0,
    const ushort* __restrict__ w1f, const float* __restrict__ ac1,
    const ushort* __restrict__ w2f, const float* __restrict__ ac2,
    const ushort* __restrict__ w3f, const float* __restrict__ ac3,
    const ushort* __restrict__ w4f, const float* __restrict__ b4,
    const unsigned* __restrict__ inv, unsigned* __restrict__ pooled,
    float* __restrict__ slices, int n){
  constexpr int SMEM = (DEPTH==2) ? 12288 : (DEPTH==3) ? 28672 : 32768;
  __shared__ __align__(16) char smem[SMEM];
  char* X0 = smem;                  // [64][32]  bf16 swz<32>,  4KB

  int t = threadIdx.x;
  int lane = t & 63, w = t >> 6;
  int lrow = lane & 15, lgrp = lane >> 4;
  int rowbase = blockIdx.x * 64;

  // stage-1 B-frag (issued before staging; overlaps)
  bf16x8 b1 = *(const bf16x8*)(w1f + (size_t)(w*64 + lane)*8);

  // ---- X0 = bn0(feats), K padded to 32, rows >= n zeroed ----
  for (int e = t; e < 2048; e += 256){
    int row = e >> 5, k = e & 31;
    int gr = rowbase + row;
    float v = (k < 9 && gr < n) ? fmaf(feats[(size_t)gr*9 + k], ac0[k], ac0[9+k]) : 0.f;
    *(ushort*)(X0 + swz<32>(row, k*2)) = f2bf(v);
  }
  __syncthreads();

  // ---- stage 1: t1 = X0 @ w1 (wave w: cols 16w..16w+16) ----
  f32x4 acc0[4] = {};
  #pragma unroll
  for (int rb = 0; rb < 4; rb++){
    bf16x8 a = *(const bf16x8*)(X0 + swz<32>(rb*16 + lrow, lgrp*16));
    acc0[rb] = __builtin_amdgcn_mfma_f32_16x16x32_bf16(a, b1, acc0[rb], 0,0,0);
  }

  char* T1 = smem + 4096;           // [64][64] bf16 swz<64>, 8KB
  // ---- T1 = bf16(relu(bn1(t1))), rows >= n zeroed ----
  {
    int j = w*16 + lrow;
    float a1 = ac1[j], c1 = ac1[64+j];
    #pragma unroll
    for (int rb=0;rb<4;rb++)
      #pragma unroll
      for (int r=0;r<4;r++){
        int row = rb*16 + 4*lgrp + r;
        float v = fmaxf(fmaf(acc0[rb][r], a1, c1), 0.f);
        if (rowbase + row >= n) v = 0.f;
        *(ushort*)(T1 + swz<64>(row, j*2)) = f2bf(v);
      }
  }
  __syncthreads();

  // ---- stage 2: 64x64 @ 64x128 (wave w: cols 32w..32w+32) ----
  f32x4 acc1[4][2] = {};
  #pragma unroll
  for (int ks=0; ks<2; ks++){
    bf16x8 bb[2];
    #pragma unroll
    for (int f=0;f<2;f++)
      bb[f] = *(const bf16x8*)(w2f + (size_t)((ks*8 + 2*w + f)*64 + lane)*8);
    #pragma unroll
    for (int rb=0;rb<4;rb++){
      bf16x8 a = *(const bf16x8*)(T1 + swz<64>(rb*16 + lrow, ks*64 + lgrp*16));
      #pragma unroll
      for (int f=0;f<2;f++)
        acc1[rb][f] = __builtin_amdgcn_mfma_f32_16x16x32_bf16(a, bb[f], acc1[rb][f], 0,0,0);
    }
  }

  if constexpr (DEPTH == 2){
    float s[2]={0.f,0.f}, ss[2]={0.f,0.f};
    #pragma unroll
    for (int rb=0;rb<4;rb++)
      #pragma unroll
      for (int f=0;f<2;f++)
        #pragma unroll
        for (int r=0;r<4;r++){ float v=acc1[rb][f][r]; s[f]+=v; ss[f]+=v*v; }
    __syncthreads();
    float* ssum = (float*)smem;
    ssum[t] = 0.f;
    __syncthreads();
    #pragma unroll
    for (int f=0;f<2;f++){
      int j = w*32 + 16*f + lrow;
      atomicAdd(&ssum[j], s[f]); atomicAdd(&ssum[128+j], ss[f]);
    }
    __syncthreads();
    float* gsl = slices + (size_t)(blockIdx.x & (SLICES-1))*256;
    atomicAdd(&gsl[t], ssum[t]);
    return;
  }

  if constexpr (DEPTH >= 3){
  char* T2 = smem + 12288;          // [64][128] bf16 swz<128>, 16KB
  // ---- T2 = bf16(relu(bn2(t2))), rows >= n zeroed ----
  #pragma unroll
  for (int f=0;f<2;f++){
    int j = w*32 + 16*f + lrow;
    float a2 = ac2[j], c2 = ac2[128+j];
    #pragma unroll
    for (int rb=0;rb<4;rb++)
      #pragma unroll
      for (int r=0;r<4;r++){
        int row = rb*16 + 4*lgrp + r;
        float v = fmaxf(fmaf(acc1[rb][f][r], a2, c2), 0.f);
        if (rowbase + row >= n) v = 0.f;
        *(ushort*)(T2 + swz<128>(row, j*2)) = f2bf(v);
      }
  }
  __syncthreads();

  if constexpr (DEPTH == 3){
    // ---- stage 3 (stats only): two 32-col halves to cap VGPR ----
    float s3[2][2], ss3[2][2];
    #pragma unroll
    for (int h=0; h<2; h++){
      f32x4 acc2[4][2] = {};
      #pragma unroll
      for (int ks=0; ks<4; ks++){
        bf16x8 bb[2];
        #pragma unroll
        for (int f=0;f<2;f++)
          bb[f] = *(const bf16x8*)(w3f + (size_t)((ks*16 + 4*w + 2*h + f)*64 + lane)*8);
        #pragma unroll
        for (int rb=0;rb<4;rb++){
          bf16x8 a = *(const bf16x8*)(T2 + swz<128>(rb*16 + lrow, ks*64 + lgrp*16));
          #pragma unroll
          for (int f=0;f<2;f++)
            acc2[rb][f] = __builtin_amdgcn_mfma_f32_16x16x32_bf16(a, bb[f], acc2[rb][f], 0,0,0);
        }
      }
      #pragma unroll
      for (int f=0;f<2;f++){
        float s=0.f, ss=0.f;
        #pragma unroll
        for (int rb=0;rb<4;rb++)
          #pragma unroll
          for (int r=0;r<4;r++){ float v=acc2[rb][f][r]; s+=v; ss+=v*v; }
        s3[h][f]=s; ss3[h][f]=ss;
      }
    }
    __syncthreads();
    float* ssum = (float*)smem;
    for (int e=t; e<512; e+=256) ssum[e] = 0.f;
    __syncthreads();
    #pragma unroll
    for (int h=0;h<2;h++)
      #pragma unroll
      for (int f=0;f<2;f++){
        int j = 64*w + 32*h + 16*f + lrow;
        atomicAdd(&ssum[j], s3[h][f]); atomicAdd(&ssum[256+j], ss3[h][f]);
      }
    __syncthreads();
    float* gsl = slices + (size_t)(blockIdx.x & (SLICES-1))*512;
    for (int e=t; e<512; e+=256) atomicAdd(&gsl[e], ssum[e]);
    return;
  }

  if constexpr (DEPTH == 4){
  // ---- stage 3 full into registers: wave w owns cols 64w..64w+64 ----
  f32x4 acc2[4][4] = {};
  #pragma unroll
  for (int ks=0; ks<4; ks++){
    bf16x8 bb[4];
    #pragma unroll
    for (int f=0;f<4;f++)
      bb[f] = *(const bf16x8*)(w3f + (size_t)((ks*16 + 4*w + f)*64 + lane)*8);
    #pragma unroll
    for (int rb=0;rb<4;rb++){
      bf16x8 a = *(const bf16x8*)(T2 + swz<128>(rb*16 + lrow, ks*64 + lgrp*16));
      #pragma unroll
      for (int f=0;f<4;f++)
        acc2[rb][f] = __builtin_amdgcn_mfma_f32_16x16x32_bf16(a, bb[f], acc2[rb][f], 0,0,0);
    }
  }
  __syncthreads();   // T2 (and X0/T1) dead -> X3 aliases smem base

  // ---- X3 = bf16(relu(bn3(t3))) at smem+0, [64][256] swz<256>, 32KB ----
  char* X3 = smem;
  #pragma unroll
  for (int f=0;f<4;f++){
    int j = 64*w + 16*f + lrow;
    float a3 = ac3[j], c3 = ac3[256+j];
    #pragma unroll
    for (int rb=0;rb<4;rb++)
      #pragma unroll
      for (int r=0;r<4;r++){
        int row = rb*16 + 4*lgrp + r;
        float v = fmaxf(fmaf(acc2[rb][f][r], a3, c3), 0.f);
        if (rowbase + row >= n) v = 0.f;
        *(ushort*)(X3 + swz<256>(row, j*2)) = f2bf(v);
      }
  }
  __syncthreads();

  // ---- stage 4: 64x256 @ 256x64 (wave w: cols 16w..16w+16) ----
  f32x4 acc3[4] = {};
  #pragma unroll
  for (int ks=0; ks<8; ks++){
    bf16x8 b = *(const bf16x8*)(w4f + (size_t)((ks*4 + w)*64 + lane)*8);
    #pragma unroll
    for (int rb=0;rb<4;rb++){
      bf16x8 a = *(const bf16x8*)(X3 + swz<256>(rb*16 + lrow, ks*64 + lgrp*16));
      acc3[rb] = __builtin_amdgcn_mfma_f32_16x16x32_bf16(a, b, acc3[rb], 0,0,0);
    }
  }

  // ---- scatter-max ----
  {
    int j = w*16 + lrow;
    float bias4 = b4[j];
    #pragma unroll
    for (int rb=0;rb<4;rb++)
      #pragma unroll
      for (int r=0;r<4;r++){
        int gr = rowbase + 16*rb + 4*lgrp + r;
        if (gr < n){
          unsigned seg = inv[gr];
          atomicMax(&pooled[(size_t)seg*64 + j], fmap(acc3[rb][r] + bias4));
        }
      }
  }
  } // DEPTH==4
  } // DEPTH>=3
}

// ---------------- projection: out = relu(pooled @ wp + bp) ----------------
__global__ __launch_bounds__(256) void k_proj(const unsigned* __restrict__ pooled,
    const float* __restrict__ wp, const float* __restrict__ bp,
    const unsigned* __restrict__ boff, float* __restrict__ out, int n){
  __shared__ float wps[64][16];
  __shared__ float pl[16][66];
  int t = threadIdx.x;
  for (int e=t; e<1024; e+=256) wps[e>>4][e&15] = wp[e];
  unsigned M = boff[108];
  int rowbase = blockIdx.x*16;
  #pragma unroll
  for (int p=0;p<4;p++){
    int e = t + p*256;
    int r = e >> 6, k = e & 63;
    int gr = rowbase + r;
    float f = 0.f;
    if (gr < (int)M) f = funmap(pooled[(size_t)gr*64 + k]);
    pl[r][k] = f;
  }
  __syncthreads();
  int r = t >> 4, j = t & 15;
  int gr = rowbase + r;
  if (gr < n){
    float acc = bp[j];
    #pragma unroll
    for (int k=0;k<64;k++) acc = fmaf(pl[r][k], wps[k][j], acc);
    out[(size_t)gr*16 + j] = fmaxf(acc, 0.f);
  }
}

extern "C" void kernel_launch(void* const* d_in, const int* in_sizes, int n_in,
                              void* d_out, int out_size, void* d_ws, size_t ws_size,
                              hipStream_t stream){
  (void)n_in; (void)out_size;
  const float* feats  = (const float*)d_in[0];
  const int*   coords = (const int*)d_in[1];
  const float* g0=(const float*)d_in[2];  const float* bb0=(const float*)d_in[3];
  const float* g1=(const float*)d_in[4];  const float* bb1=(const float*)d_in[5];
  const float* g2=(const float*)d_in[6];  const float* bb2=(const float*)d_in[7];
  const float* g3=(const float*)d_in[8];  const float* bb3=(const float*)d_in[9];
  const float* w1=(const float*)d_in[10]; const float* b1=(const float*)d_in[11];
  const float* w2=(const float*)d_in[12];
  const float* w3=(const float*)d_in[14];
  const float* w4=(const float*)d_in[16]; const float* b4=(const float*)d_in[17];
  const float* wp=(const float*)d_in[18]; const float* bp=(const float*)d_in[19];
  (void)b1;
  int n = in_sizes[0]/9;

  char* ws = (char*)d_ws;
  size_t off = 0;
  auto alloc = [&](size_t bytes){ size_t o = off; off = (off + bytes + 255) & ~(size_t)255; return o; };
  size_t o_cnt  = alloc((size_t)NKEYS*4);            // zeroed
  size_t o_sl0  = alloc((size_t)SLICES*54*4);        // zeroed
  size_t o_sl2  = alloc((size_t)SLICES*256*4);       // zeroed
  size_t o_sl3  = alloc((size_t)SLICES*512*4);       // zeroed
  size_t zero_end = off;
  size_t o_rloc = alloc((size_t)NKEYS*4);
  size_t o_bsum = alloc(128*4);
  size_t o_boff = alloc(128*4);
  size_t o_ac0  = alloc(18*4);
  size_t o_ac1  = alloc(128*4);
  size_t o_ac2  = alloc(256*4);
  size_t o_ac3  = alloc(512*4);
  size_t o_w1f  = alloc(2048*2);
  size_t o_w2f  = alloc(8192*2);
  size_t o_w3f  = alloc(32768*2);
  size_t o_w4f  = alloc(16384*2);
  size_t o_inv  = alloc((size_t)n*4);
  size_t npool = (n < NKEYS ? (size_t)n : (size_t)NKEYS);
  size_t pool_bytes = npool*64*4;
  size_t o_pool = alloc(pool_bytes);                 // zeroed
  if (ws_size < off) return;                         // clean fail if ws too small

  unsigned* cnt  = (unsigned*)(ws + o_cnt);
  unsigned* rloc = (unsigned*)(ws + o_rloc);
  unsigned* bsum = (unsigned*)(ws + o_bsum);
  unsigned* boff = (unsigned*)(ws + o_boff);
  unsigned* inv  = (unsigned*)(ws + o_inv);
  float* sl0 = (float*)(ws + o_sl0);
  float* sl2 = (float*)(ws + o_sl2);
  float* sl3 = (float*)(ws + o_sl3);
  float* ac0 = (float*)(ws + o_ac0);
  float* ac1 = (float*)(ws + o_ac1);
  float* ac2 = (float*)(ws + o_ac2);
  float* ac3 = (float*)(ws + o_ac3);
  ushort* w1f = (ushort*)(ws + o_w1f);
  ushort* w2f = (ushort*)(ws + o_w2f);
  ushort* w3f = (ushort*)(ws + o_w3f);
  ushort* w4f = (ushort*)(ws + o_w4f);
  unsigned* pooled = (unsigned*)(ws + o_pool);

  float* out_pool = (float*)d_out;
  float* out_unq  = out_pool + (size_t)n*16;

  {
    size_t n16 = zero_end/16;
    int zb = (int)((n16 + 255)/256); if (zb > 2048) zb = 2048;
    k_zero<<<zb,256,0,stream>>>((uint4*)ws, n16);
  }
  {
    size_t n16 = pool_bytes/16;
    int zb = (int)((n16 + 255)/256); if (zb > 2048) zb = 2048;
    k_zero<<<zb,256,0,stream>>>((uint4*)(ws + o_pool), n16);
  }

  // weight prep (bf16, B-fragment order)
  k_wprep<<<8,256,0,stream>>>(w1, w1f, 9, 64);
  k_wprep<<<32,256,0,stream>>>(w2, w2f, 64, 128);
  k_wprep<<<128,256,0,stream>>>(w3, w3f, 128, 256);
  k_wprep<<<64,256,0,stream>>>(w4, w4f, 256, 64);

  int nb = (n + 255)/256;
  k_keys<<<nb,256,0,stream>>>(coords, cnt, n);
  k_scan1<<<NKEYS/1024,256,0,stream>>>(cnt, rloc, bsum);
  k_scan2<<<1,128,0,stream>>>(bsum, boff);
  k_unq<<<(NKEYS+255)/256,256,0,stream>>>(cnt, rloc, boff, out_unq);
  k_pad<<<nb,256,0,stream>>>(boff, out_unq, n);
  k_inv<<<nb,256,0,stream>>>(coords, rloc, boff, inv, n);

  // feats moments -> ac0 + analytic ac1 (no DEPTH-1 pass needed)
  k_stats0x<<<512,256,0,stream>>>(feats, sl0, n);
  k_fin01<<<1,64,0,stream>>>(sl0, 1.f/(float)n, g0, bb0, g1, bb1, w1, ac0, ac1);

  int gb = (n+63)/64;
  k_chain<2><<<gb,256,0,stream>>>(feats, ac0, w1f, ac1, w2f, ac2, w3f, ac3, w4f, b4, inv, pooled, sl2, n);
  k_fin<<<2,64,0,stream>>>(sl2, 128, 1.f/(float)n, g2, bb2, ac2);

  k_chain<3><<<gb,256,0,stream>>>(feats, ac0, w1f, ac1, w2f, ac2, w3f, ac3, w4f, b4, inv, pooled, sl3, n);
  k_fin<<<4,64,0,stream>>>(sl3, 256, 1.f/(float)n, g3, bb3, ac3);

  k_chain<4><<<gb,256,0,stream>>>(feats, ac0, w1f, ac1, w2f, ac2, w3f, ac3, w4f, b4, inv, pooled, nullptr, n);

  k_proj<<<(n+15)/16,256,0,stream>>>(pooled, wp, bp, boff, out_pool, n);
}